// Round 1
// baseline (2604.244 us; speedup 1.0000x reference)
//
#include <hip/hip_runtime.h>

#define NN 50000
#define EE 600000
#define FF 128
#define HH 8
#define CC 16
#define DD 128

// ---------------------------------------------------------------------------
// K0: fold lin_edge_w + att_edge into M[8][8]; fold encoder layer-2 through M:
//     P[c][h] = sum_k enc_w2[k,c] * M[k,h];  q[h] = sum_k enc_b2[k] * M[k,h]
// ---------------------------------------------------------------------------
__global__ void k_precompute(const float* __restrict__ lew1, const float* __restrict__ ae1,
                             const float* __restrict__ lew2, const float* __restrict__ ae2,
                             const float* __restrict__ enc_w2, const float* __restrict__ enc_b2,
                             float* __restrict__ P1, float* __restrict__ q1,
                             float* __restrict__ P2, float* __restrict__ q2) {
    __shared__ float sM1[64], sM2[64];
    int t = threadIdx.x;  // 128 threads
    {
        int kk = (t & 63) >> 3, h = t & 7;
        const float* lew = (t < 64) ? lew1 : lew2;
        const float* ae  = (t < 64) ? ae1  : ae2;
        float s = 0.f;
        for (int c = 0; c < 16; ++c) s += lew[(h * 16 + c) * 8 + kk] * ae[h * 16 + c];
        if (t < 64) sM1[kk * 8 + h] = s; else sM2[kk * 8 + h] = s;
    }
    __syncthreads();
    int c = t >> 3, h = t & 7;
    float p1 = 0.f, p2 = 0.f;
    for (int k = 0; k < 8; ++k) {
        float w = enc_w2[k * 16 + c];
        p1 += w * sM1[k * 8 + h];
        p2 += w * sM2[k * 8 + h];
    }
    P1[c * 8 + h] = p1;
    P2[c * 8 + h] = p2;
    if (t < 8) {
        float s1 = 0.f, s2 = 0.f;
        for (int k = 0; k < 8; ++k) { float b = enc_b2[k]; s1 += b * sM1[k * 8 + t]; s2 += b * sM2[k * 8 + t]; }
        q1[t] = s1; q2[t] = s2;
    }
}

// ---------------------------------------------------------------------------
// K1: node squared norms
// ---------------------------------------------------------------------------
__global__ void k_norms(const float* __restrict__ x, float* __restrict__ norms) {
    int wid = threadIdx.x >> 6, lane = threadIdx.x & 63;
    int row = blockIdx.x * 4 + wid;
    if (row >= NN) return;
    const float* xr = x + (size_t)row * FF;
    float a = xr[lane], b = xr[lane + 64];
    float s = a * a + b * b;
    for (int off = 1; off < 64; off <<= 1) s += __shfl_xor(s, off, 64);
    if (lane == 0) norms[row] = s;
}

// ---------------------------------------------------------------------------
// K2: edge encoder (wave per edge): dot product, tiny MLP, write folded
//     a_edge for both convs; accumulate sums for self-loop mean.
// ---------------------------------------------------------------------------
__global__ void k_encoder(const float* __restrict__ x, const int* __restrict__ ei,
                          const float* __restrict__ norms,
                          const float* __restrict__ enc_w1, const float* __restrict__ enc_b1,
                          const float* __restrict__ P1, const float* __restrict__ q1,
                          const float* __restrict__ P2, const float* __restrict__ q2,
                          float* __restrict__ ae1out, float* __restrict__ ae2out,
                          float* __restrict__ sums) {
    __shared__ float sW1[64], sB1[16], sP1[128], sq1[8], sP2[128], sq2[8], ssum[16];
    int t = threadIdx.x;
    if (t < 64) sW1[t] = enc_w1[t];
    if (t < 16) { sB1[t] = enc_b1[t]; ssum[t] = 0.f; }
    if (t >= 64 && t < 192) { int i = t - 64; sP1[i] = P1[i]; sP2[i] = P2[i]; }
    if (t >= 192 && t < 200) { int i = t - 192; sq1[i] = q1[i]; sq2[i] = q2[i]; }
    __syncthreads();
    int wid = t >> 6, lane = t & 63;
    int e = blockIdx.x * 4 + wid;
    if (e < EE) {
        int s_ = ei[e], d_ = ei[EE + e];
        const float* xa = x + (size_t)s_ * FF;
        const float* xb = x + (size_t)d_ * FF;
        float dot = xa[lane] * xb[lane] + xa[lane + 64] * xb[lane + 64];
        for (int off = 1; off < 64; off <<= 1) dot += __shfl_xor(dot, off, 64);
        float ni = norms[s_], nj = norms[d_];
        float ef0 = dot, ef1 = ni + nj - 2.f * dot, ef2 = ni, ef3 = nj;
        float hid[16];
        #pragma unroll
        for (int c = 0; c < 16; ++c) {
            float v = sW1[c * 4 + 0] * ef0 + sW1[c * 4 + 1] * ef1 +
                      sW1[c * 4 + 2] * ef2 + sW1[c * 4 + 3] * ef3 + sB1[c];
            hid[c] = v > 0.f ? v : 0.f;
        }
        if (lane < 16) {
            int h = lane & 7;
            const float* P = (lane < 8) ? sP1 : sP2;
            const float* q = (lane < 8) ? sq1 : sq2;
            float a = q[h];
            #pragma unroll
            for (int c = 0; c < 16; ++c) a += hid[c] * P[c * 8 + h];
            if (lane < 8) ae1out[(size_t)e * 8 + h] = a;
            else          ae2out[(size_t)e * 8 + h] = a;
            atomicAdd(&ssum[lane], a);
        }
    }
    __syncthreads();
    if (t < 16) atomicAdd(&sums[t], ssum[t]);
}

// K3: self-loop folded edge score = mean over edges (linear fold)
__global__ void k_selfedge(const float* __restrict__ sums, float* __restrict__ se1, float* __restrict__ se2) {
    int t = threadIdx.x;
    if (t < 8) se1[t] = sums[t] * (1.f / (float)EE);
    else if (t < 16) se2[t - 8] = sums[t] * (1.f / (float)EE);
}

// ---------------------------------------------------------------------------
// CSR build by dst: histogram, block scan, scatter
// ---------------------------------------------------------------------------
__global__ void k_hist(const int* __restrict__ ei, int* __restrict__ deg) {
    int e = blockIdx.x * 256 + threadIdx.x;
    if (e < EE) atomicAdd(&deg[ei[EE + e]], 1);
}

__global__ void k_scan(const int* __restrict__ deg, int* __restrict__ rowptr, int* __restrict__ cursor) {
    __shared__ int buf[1024];
    __shared__ int carry;
    int t = threadIdx.x;
    if (t == 0) carry = 0;
    __syncthreads();
    for (int base = 0; base < NN; base += 1024) {
        int v = (base + t < NN) ? deg[base + t] : 0;
        buf[t] = v;
        __syncthreads();
        for (int off = 1; off < 1024; off <<= 1) {
            int tv = (t >= off) ? buf[t - off] : 0;
            __syncthreads();
            buf[t] += tv;
            __syncthreads();
        }
        int ex = carry + buf[t] - v;
        if (base + t < NN) { rowptr[base + t] = ex; cursor[base + t] = ex; }
        __syncthreads();
        if (t == 0) carry += buf[1023];
        __syncthreads();
    }
    if (t == 0) rowptr[NN] = carry;
}

__global__ void k_scatter(const int* __restrict__ ei, int* __restrict__ cursor,
                          int* __restrict__ srt_src, int* __restrict__ srt_eid) {
    int e = blockIdx.x * 256 + threadIdx.x;
    if (e < EE) {
        int d = ei[EE + e];
        int pos = atomicAdd(&cursor[d], 1);
        srt_src[pos] = ei[e];
        srt_eid[pos] = e;
    }
}

// ---------------------------------------------------------------------------
// fp32 register-tiled GEMM: out[N,128] (+)= X[N,128] @ W^T (+bias)
// W is [128, ldw] row-major (out-col major rows). 64x64 tile, 4x4/thread.
// ---------------------------------------------------------------------------
template <bool ACC, bool BIAS>
__global__ __launch_bounds__(256, 2) void k_gemm(const float* __restrict__ X,
                                                 const float* __restrict__ W, int ldw,
                                                 const float* __restrict__ bias,
                                                 float* __restrict__ out, int nrows) {
    __shared__ float xT[128][68];
    __shared__ float wT[128][68];
    int t = threadIdx.x;
    int r0 = blockIdx.x * 64, c0 = blockIdx.y * 64;
    #pragma unroll
    for (int it = 0; it < 8; ++it) {
        int idx = t + it * 256;
        int kc = idx & 31, r = idx >> 5;
        float4 v = make_float4(0.f, 0.f, 0.f, 0.f);
        if (r0 + r < nrows) v = *(const float4*)(X + (size_t)(r0 + r) * 128 + kc * 4);
        xT[kc * 4 + 0][r] = v.x; xT[kc * 4 + 1][r] = v.y;
        xT[kc * 4 + 2][r] = v.z; xT[kc * 4 + 3][r] = v.w;
        float4 wv = *(const float4*)(W + (size_t)(c0 + r) * ldw + kc * 4);
        wT[kc * 4 + 0][r] = wv.x; wT[kc * 4 + 1][r] = wv.y;
        wT[kc * 4 + 2][r] = wv.z; wT[kc * 4 + 3][r] = wv.w;
    }
    __syncthreads();
    int tx = t & 15, ty = t >> 4;
    int rl = ty * 4, cl = tx * 4;
    float acc[4][4] = {};
    #pragma unroll 4
    for (int k = 0; k < 128; ++k) {
        float4 xa = *(const float4*)&xT[k][rl];
        float4 wa = *(const float4*)&wT[k][cl];
        float xr[4] = {xa.x, xa.y, xa.z, xa.w};
        float wc[4] = {wa.x, wa.y, wa.z, wa.w};
        #pragma unroll
        for (int i = 0; i < 4; ++i)
            #pragma unroll
            for (int j = 0; j < 4; ++j) acc[i][j] += xr[i] * wc[j];
    }
    #pragma unroll
    for (int i = 0; i < 4; ++i) {
        int r = r0 + rl + i;
        if (r < nrows) {
            #pragma unroll
            for (int j = 0; j < 4; ++j) {
                int c = c0 + cl + j;
                float v = acc[i][j];
                if (BIAS) v += bias[c];
                if (ACC) v += out[(size_t)r * 128 + c];
                out[(size_t)r * 128 + c] = v;
            }
        }
    }
}

// ---------------------------------------------------------------------------
// per-node attention scores a_src/a_dst (wave per row)
// ---------------------------------------------------------------------------
__global__ void k_att(const float* __restrict__ xs, const float* __restrict__ att_src,
                      const float* __restrict__ att_dst,
                      float* __restrict__ a_src, float* __restrict__ a_dst) {
    int wid = threadIdx.x >> 6, lane = threadIdx.x & 63;
    int row = blockIdx.x * 4 + wid;
    if (row >= NN) return;
    const float* xr = xs + (size_t)row * 128;
    float v0 = xr[lane], v1 = xr[lane + 64];
    float s0 = v0 * att_src[lane], s1 = v1 * att_src[64 + lane];
    float d0 = v0 * att_dst[lane], d1 = v1 * att_dst[64 + lane];
    for (int off = 1; off < 16; off <<= 1) {
        s0 += __shfl_xor(s0, off, 64); s1 += __shfl_xor(s1, off, 64);
        d0 += __shfl_xor(d0, off, 64); d1 += __shfl_xor(d1, off, 64);
    }
    if ((lane & 15) == 0) {
        int h = lane >> 4;
        a_src[row * 8 + h] = s0;     a_src[row * 8 + 4 + h] = s1;
        a_dst[row * 8 + h] = d0;     a_dst[row * 8 + 4 + h] = d1;
    }
}

// ---------------------------------------------------------------------------
// aggregation + softmax-normalize + bias + ELU + residual + LayerNorm
// one 128-thread block per destination node
// ---------------------------------------------------------------------------
__global__ void k_agg(const int* __restrict__ rowptr, const int* __restrict__ srt_src,
                      const int* __restrict__ srt_eid,
                      const float* __restrict__ ae, const float* __restrict__ a_src,
                      const float* __restrict__ a_dst, const float* __restrict__ se,
                      const float* __restrict__ xs, const float* __restrict__ res,
                      const float* __restrict__ bias, const float* __restrict__ gamma,
                      const float* __restrict__ beta, float* __restrict__ outh) {
    int i = blockIdx.x;
    int t = threadIdx.x;  // 128
    int h = t >> 4;
    float adst = a_dst[i * 8 + h];
    int b = rowptr[i], en = rowptr[i + 1];
    float acc = 0.f, denom = 0.f;
    for (int e = b; e < en; ++e) {
        int s_ = srt_src[e];
        int eid = srt_eid[e];
        float al = a_src[s_ * 8 + h] + adst + ae[(size_t)eid * 8 + h];
        al = al > 0.f ? al : 0.2f * al;
        float w = __expf(al);
        denom += w;
        acc += w * xs[(size_t)s_ * 128 + t];
    }
    {   // self loop (mean edge-attr folded to se[h])
        float al = a_src[i * 8 + h] + adst + se[h];
        al = al > 0.f ? al : 0.2f * al;
        float w = __expf(al);
        denom += w;
        acc += w * xs[(size_t)i * 128 + t];
    }
    float val = acc / (denom + 1e-16f);
    val += bias[t];
    val = val > 0.f ? val : (__expf(val) - 1.f);            // ELU
    val += res[(size_t)i * 128 + t];                        // residual
    // LayerNorm over 128 features
    float s = val, q = val * val;
    for (int off = 1; off < 64; off <<= 1) { s += __shfl_xor(s, off, 64); q += __shfl_xor(q, off, 64); }
    __shared__ float s2[2], q2[2];
    if ((t & 63) == 0) { s2[t >> 6] = s; q2[t >> 6] = q; }
    __syncthreads();
    float mu = (s2[0] + s2[1]) * (1.f / 128.f);
    float var = (q2[0] + q2[1]) * (1.f / 128.f) - mu * mu;
    float r = rsqrtf(var + 1e-5f);
    outh[(size_t)i * 128 + t] = (val - mu) * r * gamma[t] + beta[t];
}

// ---------------------------------------------------------------------------
extern "C" void kernel_launch(void* const* d_in, const int* in_sizes, int n_in,
                              void* d_out, int out_size, void* d_ws, size_t ws_size,
                              hipStream_t stream) {
    const float* x        = (const float*)d_in[0];
    const int*   ei       = (const int*)d_in[1];
    const float* enc_w1   = (const float*)d_in[2];
    const float* enc_b1   = (const float*)d_in[3];
    const float* enc_w2   = (const float*)d_in[4];
    const float* enc_b2   = (const float*)d_in[5];
    const float* in_w     = (const float*)d_in[6];
    const float* in_b     = (const float*)d_in[7];
    const float* lin_w1   = (const float*)d_in[8];
    const float* att_src1 = (const float*)d_in[9];
    const float* att_dst1 = (const float*)d_in[10];
    const float* att_edge1= (const float*)d_in[11];
    const float* lin_ew1  = (const float*)d_in[12];
    const float* bias1    = (const float*)d_in[13];
    const float* lin_w2   = (const float*)d_in[14];
    const float* att_src2 = (const float*)d_in[15];
    const float* att_dst2 = (const float*)d_in[16];
    const float* att_edge2= (const float*)d_in[17];
    const float* lin_ew2  = (const float*)d_in[18];
    const float* bias2    = (const float*)d_in[19];
    const float* g1       = (const float*)d_in[20];
    const float* bn1      = (const float*)d_in[21];
    const float* g2       = (const float*)d_in[22];
    const float* bn2      = (const float*)d_in[23];
    const float* jk_w     = (const float*)d_in[24];
    const float* jk_b     = (const float*)d_in[25];
    float* out = (float*)d_out;

    char* wsp = (char*)d_ws;
    size_t off = 0;
    auto alloc = [&](size_t bytes) -> char* {
        char* p = wsp + off;
        off += (bytes + 255) & ~(size_t)255;
        return p;
    };
    float* h0    = (float*)alloc(sizeof(float) * (size_t)NN * 128);
    float* h1    = (float*)alloc(sizeof(float) * (size_t)NN * 128);
    float* h2    = (float*)alloc(sizeof(float) * (size_t)NN * 128);
    float* xs    = (float*)alloc(sizeof(float) * (size_t)NN * 128);
    float* ae1   = (float*)alloc(sizeof(float) * (size_t)EE * 8);
    float* ae2   = (float*)alloc(sizeof(float) * (size_t)EE * 8);
    float* norms = (float*)alloc(sizeof(float) * NN);
    float* a_src1= (float*)alloc(sizeof(float) * NN * 8);
    float* a_dst1= (float*)alloc(sizeof(float) * NN * 8);
    float* a_src2= (float*)alloc(sizeof(float) * NN * 8);
    float* a_dst2= (float*)alloc(sizeof(float) * NN * 8);
    float* P1    = (float*)alloc(sizeof(float) * 128);
    float* q1    = (float*)alloc(sizeof(float) * 8);
    float* P2    = (float*)alloc(sizeof(float) * 128);
    float* q2    = (float*)alloc(sizeof(float) * 8);
    float* se1   = (float*)alloc(sizeof(float) * 8);
    float* se2   = (float*)alloc(sizeof(float) * 8);
    float* sums  = (float*)alloc(sizeof(float) * 16);
    int* deg     = (int*)alloc(sizeof(int) * NN);
    int* rowptr  = (int*)alloc(sizeof(int) * (NN + 1));
    int* cursor  = (int*)alloc(sizeof(int) * NN);
    int* srt_src = (int*)alloc(sizeof(int) * EE);
    int* srt_eid = (int*)alloc(sizeof(int) * EE);
    (void)ws_size; (void)in_sizes; (void)n_in; (void)out_size;

    hipMemsetAsync(sums, 0, 16 * sizeof(float), stream);
    hipMemsetAsync(deg, 0, NN * sizeof(int), stream);

    k_precompute<<<1, 128, 0, stream>>>(lin_ew1, att_edge1, lin_ew2, att_edge2, enc_w2, enc_b2,
                                        P1, q1, P2, q2);
    k_norms<<<(NN + 3) / 4, 256, 0, stream>>>(x, norms);
    k_encoder<<<(EE + 3) / 4, 256, 0, stream>>>(x, ei, norms, enc_w1, enc_b1,
                                                P1, q1, P2, q2, ae1, ae2, sums);
    k_selfedge<<<1, 64, 0, stream>>>(sums, se1, se2);
    k_hist<<<(EE + 255) / 256, 256, 0, stream>>>(ei, deg);
    k_scan<<<1, 1024, 0, stream>>>(deg, rowptr, cursor);
    k_scatter<<<(EE + 255) / 256, 256, 0, stream>>>(ei, cursor, srt_src, srt_eid);

    dim3 gg((NN + 63) / 64, 2);
    k_gemm<false, true ><<<gg, 256, 0, stream>>>(x,  in_w,   128, in_b,    h0, NN);
    k_gemm<false, false><<<gg, 256, 0, stream>>>(x,  lin_w1, 128, nullptr, xs, NN);
    k_att<<<(NN + 3) / 4, 256, 0, stream>>>(xs, att_src1, att_dst1, a_src1, a_dst1);
    k_agg<<<NN, 128, 0, stream>>>(rowptr, srt_src, srt_eid, ae1, a_src1, a_dst1, se1,
                                  xs, h0, bias1, g1, bn1, h1);
    k_gemm<false, false><<<gg, 256, 0, stream>>>(h1, lin_w2, 128, nullptr, xs, NN);
    k_att<<<(NN + 3) / 4, 256, 0, stream>>>(xs, att_src2, att_dst2, a_src2, a_dst2);
    k_agg<<<NN, 128, 0, stream>>>(rowptr, srt_src, srt_eid, ae2, a_src2, a_dst2, se2,
                                  xs, h1, bias2, g2, bn2, h2);
    k_gemm<false, true ><<<gg, 256, 0, stream>>>(h0, jk_w + 0,   384, jk_b,    out, NN);
    k_gemm<true,  false><<<gg, 256, 0, stream>>>(h1, jk_w + 128, 384, nullptr, out, NN);
    k_gemm<true,  false><<<gg, 256, 0, stream>>>(h2, jk_w + 256, 384, nullptr, out, NN);
}

// Round 2
// 933.065 us; speedup vs baseline: 2.7911x; 2.7911x over previous
//
#include <hip/hip_runtime.h>

#define NN 50000
#define EE 600000
#define FF 128
#define HH 8
#define CC 16
#define DD 128

// ---------------------------------------------------------------------------
// K0: fold lin_edge_w + att_edge into M[8][8]; fold encoder layer-2 through M:
//     P[c][h] = sum_k enc_w2[k,c] * M[k,h];  q[h] = sum_k enc_b2[k] * M[k,h]
// ---------------------------------------------------------------------------
__global__ void k_precompute(const float* __restrict__ lew1, const float* __restrict__ ae1,
                             const float* __restrict__ lew2, const float* __restrict__ ae2,
                             const float* __restrict__ enc_w2, const float* __restrict__ enc_b2,
                             float* __restrict__ P1, float* __restrict__ q1,
                             float* __restrict__ P2, float* __restrict__ q2) {
    __shared__ float sM1[64], sM2[64];
    int t = threadIdx.x;  // 128 threads
    {
        int kk = (t & 63) >> 3, h = t & 7;
        const float* lew = (t < 64) ? lew1 : lew2;
        const float* ae  = (t < 64) ? ae1  : ae2;
        float s = 0.f;
        for (int c = 0; c < 16; ++c) s += lew[(h * 16 + c) * 8 + kk] * ae[h * 16 + c];
        if (t < 64) sM1[kk * 8 + h] = s; else sM2[kk * 8 + h] = s;
    }
    __syncthreads();
    int c = t >> 3, h = t & 7;
    float p1 = 0.f, p2 = 0.f;
    for (int k = 0; k < 8; ++k) {
        float w = enc_w2[k * 16 + c];
        p1 += w * sM1[k * 8 + h];
        p2 += w * sM2[k * 8 + h];
    }
    P1[c * 8 + h] = p1;
    P2[c * 8 + h] = p2;
    if (t < 8) {
        float s1 = 0.f, s2 = 0.f;
        for (int k = 0; k < 8; ++k) { float b = enc_b2[k]; s1 += b * sM1[k * 8 + t]; s2 += b * sM2[k * 8 + t]; }
        q1[t] = s1; q2[t] = s2;
    }
}

// ---------------------------------------------------------------------------
// K1: node squared norms
// ---------------------------------------------------------------------------
__global__ void k_norms(const float* __restrict__ x, float* __restrict__ norms) {
    int wid = threadIdx.x >> 6, lane = threadIdx.x & 63;
    int row = blockIdx.x * 4 + wid;
    if (row >= NN) return;
    const float* xr = x + (size_t)row * FF;
    float a = xr[lane], b = xr[lane + 64];
    float s = a * a + b * b;
    for (int off = 1; off < 64; off <<= 1) s += __shfl_xor(s, off, 64);
    if (lane == 0) norms[row] = s;
}

// ---------------------------------------------------------------------------
// K2: edge encoder (wave per edge): dot product, tiny MLP, write folded
//     a_edge for both convs. NO global accumulation here (was a 150K-deep
//     same-address atomic chain = 73% of total runtime).
// ---------------------------------------------------------------------------
__global__ void k_encoder(const float* __restrict__ x, const int* __restrict__ ei,
                          const float* __restrict__ norms,
                          const float* __restrict__ enc_w1, const float* __restrict__ enc_b1,
                          const float* __restrict__ P1, const float* __restrict__ q1,
                          const float* __restrict__ P2, const float* __restrict__ q2,
                          float* __restrict__ ae1out, float* __restrict__ ae2out) {
    __shared__ float sW1[64], sB1[16], sP1[128], sq1[8], sP2[128], sq2[8];
    int t = threadIdx.x;
    if (t < 64) sW1[t] = enc_w1[t];
    if (t < 16) sB1[t] = enc_b1[t];
    if (t >= 64 && t < 192) { int i = t - 64; sP1[i] = P1[i]; sP2[i] = P2[i]; }
    if (t >= 192 && t < 200) { int i = t - 192; sq1[i] = q1[i]; sq2[i] = q2[i]; }
    __syncthreads();
    int wid = t >> 6, lane = t & 63;
    int e = blockIdx.x * 4 + wid;
    if (e >= EE) return;
    int s_ = ei[e], d_ = ei[EE + e];
    const float* xa = x + (size_t)s_ * FF;
    const float* xb = x + (size_t)d_ * FF;
    float dot = xa[lane] * xb[lane] + xa[lane + 64] * xb[lane + 64];
    for (int off = 1; off < 64; off <<= 1) dot += __shfl_xor(dot, off, 64);
    float ni = norms[s_], nj = norms[d_];
    float ef0 = dot, ef1 = ni + nj - 2.f * dot, ef2 = ni, ef3 = nj;
    float hid[16];
    #pragma unroll
    for (int c = 0; c < 16; ++c) {
        float v = sW1[c * 4 + 0] * ef0 + sW1[c * 4 + 1] * ef1 +
                  sW1[c * 4 + 2] * ef2 + sW1[c * 4 + 3] * ef3 + sB1[c];
        hid[c] = v > 0.f ? v : 0.f;
    }
    if (lane < 16) {
        int h = lane & 7;
        const float* P = (lane < 8) ? sP1 : sP2;
        const float* q = (lane < 8) ? sq1 : sq2;
        float a = q[h];
        #pragma unroll
        for (int c = 0; c < 16; ++c) a += hid[c] * P[c * 8 + h];
        if (lane < 8) ae1out[(size_t)e * 8 + h] = a;
        else          ae2out[(size_t)e * 8 + h] = a;
    }
}

// ---------------------------------------------------------------------------
// K2b: grid-stride reduction of ae1/ae2 per head -> sums[16]
// (stride is a multiple of 8, so each thread's elements all share h = tid&7)
// ---------------------------------------------------------------------------
__global__ void k_redsum(const float* __restrict__ a1, const float* __restrict__ a2,
                         float* __restrict__ sums) {
    int tid = threadIdx.x;  // 256
    int gid = blockIdx.x * 256 + tid;
    int stride = gridDim.x * 256;
    float s1 = 0.f, s2 = 0.f;
    for (int i = gid; i < EE * 8; i += stride) { s1 += a1[i]; s2 += a2[i]; }
    for (int off = 8; off < 64; off <<= 1) { s1 += __shfl_xor(s1, off, 64); s2 += __shfl_xor(s2, off, 64); }
    __shared__ float b1[4][8], b2[4][8];
    int wid = tid >> 6, lane = tid & 63;
    if (lane < 8) { b1[wid][lane] = s1; b2[wid][lane] = s2; }
    __syncthreads();
    if (tid < 8) {
        float t1 = b1[0][tid] + b1[1][tid] + b1[2][tid] + b1[3][tid];
        float t2 = b2[0][tid] + b2[1][tid] + b2[2][tid] + b2[3][tid];
        atomicAdd(&sums[tid], t1);
        atomicAdd(&sums[8 + tid], t2);
    }
}

// K3: self-loop folded edge score = mean over edges (linear fold)
__global__ void k_selfedge(const float* __restrict__ sums, float* __restrict__ se1, float* __restrict__ se2) {
    int t = threadIdx.x;
    if (t < 8) se1[t] = sums[t] * (1.f / (float)EE);
    else if (t < 16) se2[t - 8] = sums[t] * (1.f / (float)EE);
}

// ---------------------------------------------------------------------------
// CSR build by dst: histogram, block scan, scatter
// ---------------------------------------------------------------------------
__global__ void k_hist(const int* __restrict__ ei, int* __restrict__ deg) {
    int e = blockIdx.x * 256 + threadIdx.x;
    if (e < EE) atomicAdd(&deg[ei[EE + e]], 1);
}

__global__ void k_scan(const int* __restrict__ deg, int* __restrict__ rowptr, int* __restrict__ cursor) {
    __shared__ int buf[1024];
    __shared__ int carry;
    int t = threadIdx.x;
    if (t == 0) carry = 0;
    __syncthreads();
    for (int base = 0; base < NN; base += 1024) {
        int v = (base + t < NN) ? deg[base + t] : 0;
        buf[t] = v;
        __syncthreads();
        for (int off = 1; off < 1024; off <<= 1) {
            int tv = (t >= off) ? buf[t - off] : 0;
            __syncthreads();
            buf[t] += tv;
            __syncthreads();
        }
        int ex = carry + buf[t] - v;
        if (base + t < NN) { rowptr[base + t] = ex; cursor[base + t] = ex; }
        __syncthreads();
        if (t == 0) carry += buf[1023];
        __syncthreads();
    }
    if (t == 0) rowptr[NN] = carry;
}

__global__ void k_scatter(const int* __restrict__ ei, int* __restrict__ cursor,
                          int* __restrict__ srt_src, int* __restrict__ srt_eid) {
    int e = blockIdx.x * 256 + threadIdx.x;
    if (e < EE) {
        int d = ei[EE + e];
        int pos = atomicAdd(&cursor[d], 1);
        srt_src[pos] = ei[e];
        srt_eid[pos] = e;
    }
}

// ---------------------------------------------------------------------------
// fp32 register-tiled GEMM: out[N,128] (+)= X[N,128] @ W^T (+bias)
// W is [128, ldw] row-major (out-col major rows). 64x64 tile, 4x4/thread.
// ---------------------------------------------------------------------------
template <bool ACC, bool BIAS>
__global__ __launch_bounds__(256, 2) void k_gemm(const float* __restrict__ X,
                                                 const float* __restrict__ W, int ldw,
                                                 const float* __restrict__ bias,
                                                 float* __restrict__ out, int nrows) {
    __shared__ float xT[128][68];
    __shared__ float wT[128][68];
    int t = threadIdx.x;
    int r0 = blockIdx.x * 64, c0 = blockIdx.y * 64;
    #pragma unroll
    for (int it = 0; it < 8; ++it) {
        int idx = t + it * 256;
        int kc = idx & 31, r = idx >> 5;
        float4 v = make_float4(0.f, 0.f, 0.f, 0.f);
        if (r0 + r < nrows) v = *(const float4*)(X + (size_t)(r0 + r) * 128 + kc * 4);
        xT[kc * 4 + 0][r] = v.x; xT[kc * 4 + 1][r] = v.y;
        xT[kc * 4 + 2][r] = v.z; xT[kc * 4 + 3][r] = v.w;
        float4 wv = *(const float4*)(W + (size_t)(c0 + r) * ldw + kc * 4);
        wT[kc * 4 + 0][r] = wv.x; wT[kc * 4 + 1][r] = wv.y;
        wT[kc * 4 + 2][r] = wv.z; wT[kc * 4 + 3][r] = wv.w;
    }
    __syncthreads();
    int tx = t & 15, ty = t >> 4;
    int rl = ty * 4, cl = tx * 4;
    float acc[4][4] = {};
    #pragma unroll 4
    for (int k = 0; k < 128; ++k) {
        float4 xa = *(const float4*)&xT[k][rl];
        float4 wa = *(const float4*)&wT[k][cl];
        float xr[4] = {xa.x, xa.y, xa.z, xa.w};
        float wc[4] = {wa.x, wa.y, wa.z, wa.w};
        #pragma unroll
        for (int i = 0; i < 4; ++i)
            #pragma unroll
            for (int j = 0; j < 4; ++j) acc[i][j] += xr[i] * wc[j];
    }
    #pragma unroll
    for (int i = 0; i < 4; ++i) {
        int r = r0 + rl + i;
        if (r < nrows) {
            #pragma unroll
            for (int j = 0; j < 4; ++j) {
                int c = c0 + cl + j;
                float v = acc[i][j];
                if (BIAS) v += bias[c];
                if (ACC) v += out[(size_t)r * 128 + c];
                out[(size_t)r * 128 + c] = v;
            }
        }
    }
}

// ---------------------------------------------------------------------------
// per-node attention scores a_src/a_dst (wave per row)
// ---------------------------------------------------------------------------
__global__ void k_att(const float* __restrict__ xs, const float* __restrict__ att_src,
                      const float* __restrict__ att_dst,
                      float* __restrict__ a_src, float* __restrict__ a_dst) {
    int wid = threadIdx.x >> 6, lane = threadIdx.x & 63;
    int row = blockIdx.x * 4 + wid;
    if (row >= NN) return;
    const float* xr = xs + (size_t)row * 128;
    float v0 = xr[lane], v1 = xr[lane + 64];
    float s0 = v0 * att_src[lane], s1 = v1 * att_src[64 + lane];
    float d0 = v0 * att_dst[lane], d1 = v1 * att_dst[64 + lane];
    for (int off = 1; off < 16; off <<= 1) {
        s0 += __shfl_xor(s0, off, 64); s1 += __shfl_xor(s1, off, 64);
        d0 += __shfl_xor(d0, off, 64); d1 += __shfl_xor(d1, off, 64);
    }
    if ((lane & 15) == 0) {
        int h = lane >> 4;
        a_src[row * 8 + h] = s0;     a_src[row * 8 + 4 + h] = s1;
        a_dst[row * 8 + h] = d0;     a_dst[row * 8 + 4 + h] = d1;
    }
}

// ---------------------------------------------------------------------------
// aggregation + softmax-normalize + bias + ELU + residual + LayerNorm
// one 128-thread block per destination node
// ---------------------------------------------------------------------------
__global__ void k_agg(const int* __restrict__ rowptr, const int* __restrict__ srt_src,
                      const int* __restrict__ srt_eid,
                      const float* __restrict__ ae, const float* __restrict__ a_src,
                      const float* __restrict__ a_dst, const float* __restrict__ se,
                      const float* __restrict__ xs, const float* __restrict__ res,
                      const float* __restrict__ bias, const float* __restrict__ gamma,
                      const float* __restrict__ beta, float* __restrict__ outh) {
    int i = blockIdx.x;
    int t = threadIdx.x;  // 128
    int h = t >> 4;
    float adst = a_dst[i * 8 + h];
    int b = rowptr[i], en = rowptr[i + 1];
    float acc = 0.f, denom = 0.f;
    for (int e = b; e < en; ++e) {
        int s_ = srt_src[e];
        int eid = srt_eid[e];
        float al = a_src[s_ * 8 + h] + adst + ae[(size_t)eid * 8 + h];
        al = al > 0.f ? al : 0.2f * al;
        float w = __expf(al);
        denom += w;
        acc += w * xs[(size_t)s_ * 128 + t];
    }
    {   // self loop (mean edge-attr folded to se[h])
        float al = a_src[i * 8 + h] + adst + se[h];
        al = al > 0.f ? al : 0.2f * al;
        float w = __expf(al);
        denom += w;
        acc += w * xs[(size_t)i * 128 + t];
    }
    float val = acc / (denom + 1e-16f);
    val += bias[t];
    val = val > 0.f ? val : (__expf(val) - 1.f);            // ELU
    val += res[(size_t)i * 128 + t];                        // residual
    // LayerNorm over 128 features
    float s = val, q = val * val;
    for (int off = 1; off < 64; off <<= 1) { s += __shfl_xor(s, off, 64); q += __shfl_xor(q, off, 64); }
    __shared__ float s2[2], q2[2];
    if ((t & 63) == 0) { s2[t >> 6] = s; q2[t >> 6] = q; }
    __syncthreads();
    float mu = (s2[0] + s2[1]) * (1.f / 128.f);
    float var = (q2[0] + q2[1]) * (1.f / 128.f) - mu * mu;
    float r = rsqrtf(var + 1e-5f);
    outh[(size_t)i * 128 + t] = (val - mu) * r * gamma[t] + beta[t];
}

// ---------------------------------------------------------------------------
extern "C" void kernel_launch(void* const* d_in, const int* in_sizes, int n_in,
                              void* d_out, int out_size, void* d_ws, size_t ws_size,
                              hipStream_t stream) {
    const float* x        = (const float*)d_in[0];
    const int*   ei       = (const int*)d_in[1];
    const float* enc_w1   = (const float*)d_in[2];
    const float* enc_b1   = (const float*)d_in[3];
    const float* enc_w2   = (const float*)d_in[4];
    const float* enc_b2   = (const float*)d_in[5];
    const float* in_w     = (const float*)d_in[6];
    const float* in_b     = (const float*)d_in[7];
    const float* lin_w1   = (const float*)d_in[8];
    const float* att_src1 = (const float*)d_in[9];
    const float* att_dst1 = (const float*)d_in[10];
    const float* att_edge1= (const float*)d_in[11];
    const float* lin_ew1  = (const float*)d_in[12];
    const float* bias1    = (const float*)d_in[13];
    const float* lin_w2   = (const float*)d_in[14];
    const float* att_src2 = (const float*)d_in[15];
    const float* att_dst2 = (const float*)d_in[16];
    const float* att_edge2= (const float*)d_in[17];
    const float* lin_ew2  = (const float*)d_in[18];
    const float* bias2    = (const float*)d_in[19];
    const float* g1       = (const float*)d_in[20];
    const float* bn1      = (const float*)d_in[21];
    const float* g2       = (const float*)d_in[22];
    const float* bn2      = (const float*)d_in[23];
    const float* jk_w     = (const float*)d_in[24];
    const float* jk_b     = (const float*)d_in[25];
    float* out = (float*)d_out;

    char* wsp = (char*)d_ws;
    size_t off = 0;
    auto alloc = [&](size_t bytes) -> char* {
        char* p = wsp + off;
        off += (bytes + 255) & ~(size_t)255;
        return p;
    };
    float* h0    = (float*)alloc(sizeof(float) * (size_t)NN * 128);
    float* h1    = (float*)alloc(sizeof(float) * (size_t)NN * 128);
    float* h2    = (float*)alloc(sizeof(float) * (size_t)NN * 128);
    float* xs    = (float*)alloc(sizeof(float) * (size_t)NN * 128);
    float* ae1   = (float*)alloc(sizeof(float) * (size_t)EE * 8);
    float* ae2   = (float*)alloc(sizeof(float) * (size_t)EE * 8);
    float* norms = (float*)alloc(sizeof(float) * NN);
    float* a_src1= (float*)alloc(sizeof(float) * NN * 8);
    float* a_dst1= (float*)alloc(sizeof(float) * NN * 8);
    float* a_src2= (float*)alloc(sizeof(float) * NN * 8);
    float* a_dst2= (float*)alloc(sizeof(float) * NN * 8);
    float* P1    = (float*)alloc(sizeof(float) * 128);
    float* q1    = (float*)alloc(sizeof(float) * 8);
    float* P2    = (float*)alloc(sizeof(float) * 128);
    float* q2    = (float*)alloc(sizeof(float) * 8);
    float* se1   = (float*)alloc(sizeof(float) * 8);
    float* se2   = (float*)alloc(sizeof(float) * 8);
    float* sums  = (float*)alloc(sizeof(float) * 16);
    int* deg     = (int*)alloc(sizeof(int) * NN);
    int* rowptr  = (int*)alloc(sizeof(int) * (NN + 1));
    int* cursor  = (int*)alloc(sizeof(int) * NN);
    int* srt_src = (int*)alloc(sizeof(int) * EE);
    int* srt_eid = (int*)alloc(sizeof(int) * EE);
    (void)ws_size; (void)in_sizes; (void)n_in; (void)out_size;

    hipMemsetAsync(sums, 0, 16 * sizeof(float), stream);
    hipMemsetAsync(deg, 0, NN * sizeof(int), stream);

    k_precompute<<<1, 128, 0, stream>>>(lin_ew1, att_edge1, lin_ew2, att_edge2, enc_w2, enc_b2,
                                        P1, q1, P2, q2);
    k_norms<<<(NN + 3) / 4, 256, 0, stream>>>(x, norms);
    k_encoder<<<(EE + 3) / 4, 256, 0, stream>>>(x, ei, norms, enc_w1, enc_b1,
                                                P1, q1, P2, q2, ae1, ae2);
    k_redsum<<<128, 256, 0, stream>>>(ae1, ae2, sums);
    k_selfedge<<<1, 64, 0, stream>>>(sums, se1, se2);
    k_hist<<<(EE + 255) / 256, 256, 0, stream>>>(ei, deg);
    k_scan<<<1, 1024, 0, stream>>>(deg, rowptr, cursor);
    k_scatter<<<(EE + 255) / 256, 256, 0, stream>>>(ei, cursor, srt_src, srt_eid);

    dim3 gg((NN + 63) / 64, 2);
    k_gemm<false, true ><<<gg, 256, 0, stream>>>(x,  in_w,   128, in_b,    h0, NN);
    k_gemm<false, false><<<gg, 256, 0, stream>>>(x,  lin_w1, 128, nullptr, xs, NN);
    k_att<<<(NN + 3) / 4, 256, 0, stream>>>(xs, att_src1, att_dst1, a_src1, a_dst1);
    k_agg<<<NN, 128, 0, stream>>>(rowptr, srt_src, srt_eid, ae1, a_src1, a_dst1, se1,
                                  xs, h0, bias1, g1, bn1, h1);
    k_gemm<false, false><<<gg, 256, 0, stream>>>(h1, lin_w2, 128, nullptr, xs, NN);
    k_att<<<(NN + 3) / 4, 256, 0, stream>>>(xs, att_src2, att_dst2, a_src2, a_dst2);
    k_agg<<<NN, 128, 0, stream>>>(rowptr, srt_src, srt_eid, ae2, a_src2, a_dst2, se2,
                                  xs, h1, bias2, g2, bn2, h2);
    k_gemm<false, true ><<<gg, 256, 0, stream>>>(h0, jk_w + 0,   384, jk_b,    out, NN);
    k_gemm<true,  false><<<gg, 256, 0, stream>>>(h1, jk_w + 128, 384, nullptr, out, NN);
    k_gemm<true,  false><<<gg, 256, 0, stream>>>(h2, jk_w + 256, 384, nullptr, out, NN);
}

// Round 3
// 776.454 us; speedup vs baseline: 3.3540x; 1.2017x over previous
//
#include <hip/hip_runtime.h>

#define NN 50000
#define EE 600000
#define FF 128
#define HH 8
#define CC 16
#define DD 128

// ---------------------------------------------------------------------------
// K0: fold lin_edge_w + att_edge into M[8][8]; fold encoder layer-2 through M:
//     P[c][h] = sum_k enc_w2[k,c] * M[k,h];  q[h] = sum_k enc_b2[k] * M[k,h]
// ---------------------------------------------------------------------------
__global__ void k_precompute(const float* __restrict__ lew1, const float* __restrict__ ae1,
                             const float* __restrict__ lew2, const float* __restrict__ ae2,
                             const float* __restrict__ enc_w2, const float* __restrict__ enc_b2,
                             float* __restrict__ P1, float* __restrict__ q1,
                             float* __restrict__ P2, float* __restrict__ q2) {
    __shared__ float sM1[64], sM2[64];
    int t = threadIdx.x;  // 128 threads
    {
        int kk = (t & 63) >> 3, h = t & 7;
        const float* lew = (t < 64) ? lew1 : lew2;
        const float* ae  = (t < 64) ? ae1  : ae2;
        float s = 0.f;
        for (int c = 0; c < 16; ++c) s += lew[(h * 16 + c) * 8 + kk] * ae[h * 16 + c];
        if (t < 64) sM1[kk * 8 + h] = s; else sM2[kk * 8 + h] = s;
    }
    __syncthreads();
    int c = t >> 3, h = t & 7;
    float p1 = 0.f, p2 = 0.f;
    for (int k = 0; k < 8; ++k) {
        float w = enc_w2[k * 16 + c];
        p1 += w * sM1[k * 8 + h];
        p2 += w * sM2[k * 8 + h];
    }
    P1[c * 8 + h] = p1;
    P2[c * 8 + h] = p2;
    if (t < 8) {
        float s1 = 0.f, s2 = 0.f;
        for (int k = 0; k < 8; ++k) { float b = enc_b2[k]; s1 += b * sM1[k * 8 + t]; s2 += b * sM2[k * 8 + t]; }
        q1[t] = s1; q2[t] = s2;
    }
}

// ---------------------------------------------------------------------------
// K1: node squared norms
// ---------------------------------------------------------------------------
__global__ void k_norms(const float* __restrict__ x, float* __restrict__ norms) {
    int wid = threadIdx.x >> 6, lane = threadIdx.x & 63;
    int row = blockIdx.x * 4 + wid;
    if (row >= NN) return;
    const float* xr = x + (size_t)row * FF;
    float a = xr[lane], b = xr[lane + 64];
    float s = a * a + b * b;
    for (int off = 1; off < 64; off <<= 1) s += __shfl_xor(s, off, 64);
    if (lane == 0) norms[row] = s;
}

// ---------------------------------------------------------------------------
// K2: edge encoder, 16 lanes per edge (4 edges per wave, 16 per block).
// Layer-1 folded: v_c = A_c*dot + B_c*ni + C_c*nj + b_c. One channel per lane.
// hid exchanged through padded LDS within the wave (no barrier needed).
// ---------------------------------------------------------------------------
__global__ void k_encoder(const float* __restrict__ x, const int* __restrict__ ei,
                          const float* __restrict__ norms,
                          const float* __restrict__ enc_w1, const float* __restrict__ enc_b1,
                          const float* __restrict__ P1, const float* __restrict__ q1,
                          const float* __restrict__ P2, const float* __restrict__ q2,
                          float* __restrict__ ae1out, float* __restrict__ ae2out) {
    __shared__ float sA[16], sB[16], sC[16], sb[16];
    __shared__ float sP[256], sq[16];
    __shared__ float hidbuf[16][17];
    int t = threadIdx.x;
    if (t < 16) {
        float w0 = enc_w1[t * 4 + 0], w1 = enc_w1[t * 4 + 1];
        float w2 = enc_w1[t * 4 + 2], w3 = enc_w1[t * 4 + 3];
        sA[t] = w0 - 2.f * w1;
        sB[t] = w1 + w2;
        sC[t] = w1 + w3;
        sb[t] = enc_b1[t];
    }
    if (t < 128) sP[t] = P1[t]; else if (t < 256) sP[t] = P2[t - 128];
    if (t >= 16 && t < 24) sq[t - 16] = q1[t - 16];
    if (t >= 24 && t < 32) sq[t - 16] = q2[t - 24];
    __syncthreads();
    int eq = t >> 4, l = t & 15;
    int e = blockIdx.x * 16 + eq;
    if (e >= EE) return;
    int s_ = ei[e], d_ = ei[EE + e];
    const float* xa = x + (size_t)s_ * FF + l * 8;
    const float* xb = x + (size_t)d_ * FF + l * 8;
    float4 a0 = *(const float4*)xa, a1 = *(const float4*)(xa + 4);
    float4 b0 = *(const float4*)xb, b1 = *(const float4*)(xb + 4);
    float dot = a0.x * b0.x + a0.y * b0.y + a0.z * b0.z + a0.w * b0.w +
                a1.x * b1.x + a1.y * b1.y + a1.z * b1.z + a1.w * b1.w;
    #pragma unroll
    for (int off = 1; off < 16; off <<= 1) dot += __shfl_xor(dot, off, 64);
    float ni = norms[s_], nj = norms[d_];
    float v = sA[l] * dot + sB[l] * ni + sC[l] * nj + sb[l];
    hidbuf[eq][l] = v > 0.f ? v : 0.f;
    // lane l -> (conv = l>>3, h = l&7)
    int conv = l >> 3, h = l & 7;
    const float* P = sP + conv * 128;
    float a = sq[conv * 8 + h];
    #pragma unroll
    for (int c = 0; c < 16; ++c) a += hidbuf[eq][c] * P[c * 8 + h];
    if (conv == 0) ae1out[(size_t)e * 8 + h] = a;
    else           ae2out[(size_t)e * 8 + h] = a;
}

// ---------------------------------------------------------------------------
// K2b: grid-stride reduction of ae1/ae2 per head -> sums[16]
// ---------------------------------------------------------------------------
__global__ void k_redsum(const float* __restrict__ a1, const float* __restrict__ a2,
                         float* __restrict__ sums) {
    int tid = threadIdx.x;  // 256
    int gid = blockIdx.x * 256 + tid;
    int stride = gridDim.x * 256;
    float s1 = 0.f, s2 = 0.f;
    for (int i = gid; i < EE * 8; i += stride) { s1 += a1[i]; s2 += a2[i]; }
    for (int off = 8; off < 64; off <<= 1) { s1 += __shfl_xor(s1, off, 64); s2 += __shfl_xor(s2, off, 64); }
    __shared__ float b1[4][8], b2[4][8];
    int wid = tid >> 6, lane = tid & 63;
    if (lane < 8) { b1[wid][lane] = s1; b2[wid][lane] = s2; }
    __syncthreads();
    if (tid < 8) {
        float t1 = b1[0][tid] + b1[1][tid] + b1[2][tid] + b1[3][tid];
        float t2 = b2[0][tid] + b2[1][tid] + b2[2][tid] + b2[3][tid];
        atomicAdd(&sums[tid], t1);
        atomicAdd(&sums[8 + tid], t2);
    }
}

// K3: self-loop folded edge score = mean over edges (linear fold)
__global__ void k_selfedge(const float* __restrict__ sums, float* __restrict__ se1, float* __restrict__ se2) {
    int t = threadIdx.x;
    if (t < 8) se1[t] = sums[t] * (1.f / (float)EE);
    else if (t < 16) se2[t - 8] = sums[t] * (1.f / (float)EE);
}

// ---------------------------------------------------------------------------
// CSR build by dst: histogram, shuffle-scan, scatter (+srt_dst)
// ---------------------------------------------------------------------------
__global__ void k_hist(const int* __restrict__ ei, int* __restrict__ deg) {
    int e = blockIdx.x * 256 + threadIdx.x;
    if (e < EE) atomicAdd(&deg[ei[EE + e]], 1);
}

__global__ void k_scan(const int* __restrict__ deg, int* __restrict__ rowptr, int* __restrict__ cursor) {
    __shared__ int wsum[16];
    __shared__ int carry;
    int t = threadIdx.x, wid = t >> 6, lane = t & 63;
    if (t == 0) carry = 0;
    __syncthreads();
    for (int base = 0; base < NN; base += 1024) {
        int v = (base + t < NN) ? deg[base + t] : 0;
        int sc = v;
        #pragma unroll
        for (int off = 1; off < 64; off <<= 1) { int n = __shfl_up(sc, off, 64); if (lane >= off) sc += n; }
        if (lane == 63) wsum[wid] = sc;
        __syncthreads();
        if (t < 16) {
            int ws = wsum[t];
            #pragma unroll
            for (int off = 1; off < 16; off <<= 1) { int n = __shfl_up(ws, off, 64); if (t >= off) ws += n; }
            wsum[t] = ws;
        }
        __syncthreads();
        int ex = carry + (wid ? wsum[wid - 1] : 0) + sc - v;
        if (base + t < NN) { rowptr[base + t] = ex; cursor[base + t] = ex; }
        __syncthreads();
        if (t == 0) carry += wsum[15];
        __syncthreads();
    }
    if (t == 0) rowptr[NN] = carry;
}

__global__ void k_scatter(const int* __restrict__ ei, int* __restrict__ cursor,
                          int* __restrict__ srt_src, int* __restrict__ srt_eid,
                          int* __restrict__ srt_dst) {
    int e = blockIdx.x * 256 + threadIdx.x;
    if (e < EE) {
        int d = ei[EE + e];
        int pos = atomicAdd(&cursor[d], 1);
        srt_src[pos] = ei[e];
        srt_eid[pos] = e;
        srt_dst[pos] = d;
    }
}

// ---------------------------------------------------------------------------
// fp32 register-tiled GEMM: out[N,128] = X[N,128] @ W^T (+bias)
// ---------------------------------------------------------------------------
template <bool BIAS>
__global__ __launch_bounds__(256, 2) void k_gemm(const float* __restrict__ X,
                                                 const float* __restrict__ W, int ldw,
                                                 const float* __restrict__ bias,
                                                 float* __restrict__ out, int nrows) {
    __shared__ float xT[128][68];
    __shared__ float wT[128][68];
    int t = threadIdx.x;
    int r0 = blockIdx.x * 64, c0 = blockIdx.y * 64;
    #pragma unroll
    for (int it = 0; it < 8; ++it) {
        int idx = t + it * 256;
        int kc = idx & 31, r = idx >> 5;
        float4 v = make_float4(0.f, 0.f, 0.f, 0.f);
        if (r0 + r < nrows) v = *(const float4*)(X + (size_t)(r0 + r) * 128 + kc * 4);
        xT[kc * 4 + 0][r] = v.x; xT[kc * 4 + 1][r] = v.y;
        xT[kc * 4 + 2][r] = v.z; xT[kc * 4 + 3][r] = v.w;
        float4 wv = *(const float4*)(W + (size_t)(c0 + r) * ldw + kc * 4);
        wT[kc * 4 + 0][r] = wv.x; wT[kc * 4 + 1][r] = wv.y;
        wT[kc * 4 + 2][r] = wv.z; wT[kc * 4 + 3][r] = wv.w;
    }
    __syncthreads();
    int tx = t & 15, ty = t >> 4;
    int rl = ty * 4, cl = tx * 4;
    float acc[4][4] = {};
    #pragma unroll 4
    for (int k = 0; k < 128; ++k) {
        float4 xa = *(const float4*)&xT[k][rl];
        float4 wa = *(const float4*)&wT[k][cl];
        float xr[4] = {xa.x, xa.y, xa.z, xa.w};
        float wc[4] = {wa.x, wa.y, wa.z, wa.w};
        #pragma unroll
        for (int i = 0; i < 4; ++i)
            #pragma unroll
            for (int j = 0; j < 4; ++j) acc[i][j] += xr[i] * wc[j];
    }
    #pragma unroll
    for (int i = 0; i < 4; ++i) {
        int r = r0 + rl + i;
        if (r < nrows) {
            #pragma unroll
            for (int j = 0; j < 4; ++j) {
                int c = c0 + cl + j;
                float v = acc[i][j];
                if (BIAS) v += bias[c];
                out[(size_t)r * 128 + c] = v;
            }
        }
    }
}

// ---------------------------------------------------------------------------
// fused JK GEMM: out = [h0 h1 h2] @ jk_w^T + jk_b  (K=384 in 3 segments)
// ---------------------------------------------------------------------------
__global__ __launch_bounds__(256, 2) void k_gemm_jk(const float* __restrict__ h0,
                                                    const float* __restrict__ h1,
                                                    const float* __restrict__ h2,
                                                    const float* __restrict__ W,
                                                    const float* __restrict__ bias,
                                                    float* __restrict__ out, int nrows) {
    __shared__ float xT[128][68];
    __shared__ float wT[128][68];
    int t = threadIdx.x;
    int r0 = blockIdx.x * 64, c0 = blockIdx.y * 64;
    int tx = t & 15, ty = t >> 4;
    int rl = ty * 4, cl = tx * 4;
    float acc[4][4] = {};
    const float* Xs[3] = {h0, h1, h2};
    for (int seg = 0; seg < 3; ++seg) {
        const float* X = Xs[seg];
        #pragma unroll
        for (int it = 0; it < 8; ++it) {
            int idx = t + it * 256;
            int kc = idx & 31, r = idx >> 5;
            float4 v = make_float4(0.f, 0.f, 0.f, 0.f);
            if (r0 + r < nrows) v = *(const float4*)(X + (size_t)(r0 + r) * 128 + kc * 4);
            xT[kc * 4 + 0][r] = v.x; xT[kc * 4 + 1][r] = v.y;
            xT[kc * 4 + 2][r] = v.z; xT[kc * 4 + 3][r] = v.w;
            float4 wv = *(const float4*)(W + (size_t)(c0 + r) * 384 + seg * 128 + kc * 4);
            wT[kc * 4 + 0][r] = wv.x; wT[kc * 4 + 1][r] = wv.y;
            wT[kc * 4 + 2][r] = wv.z; wT[kc * 4 + 3][r] = wv.w;
        }
        __syncthreads();
        #pragma unroll 4
        for (int k = 0; k < 128; ++k) {
            float4 xa = *(const float4*)&xT[k][rl];
            float4 wa = *(const float4*)&wT[k][cl];
            float xr[4] = {xa.x, xa.y, xa.z, xa.w};
            float wc[4] = {wa.x, wa.y, wa.z, wa.w};
            #pragma unroll
            for (int i = 0; i < 4; ++i)
                #pragma unroll
                for (int j = 0; j < 4; ++j) acc[i][j] += xr[i] * wc[j];
        }
        __syncthreads();
    }
    #pragma unroll
    for (int i = 0; i < 4; ++i) {
        int r = r0 + rl + i;
        if (r < nrows) {
            #pragma unroll
            for (int j = 0; j < 4; ++j) {
                int c = c0 + cl + j;
                out[(size_t)r * 128 + c] = acc[i][j] + bias[c];
            }
        }
    }
}

// ---------------------------------------------------------------------------
// per-node attention scores a_src/a_dst (wave per row)
// ---------------------------------------------------------------------------
__global__ void k_att(const float* __restrict__ xs, const float* __restrict__ att_src,
                      const float* __restrict__ att_dst,
                      float* __restrict__ a_src, float* __restrict__ a_dst) {
    int wid = threadIdx.x >> 6, lane = threadIdx.x & 63;
    int row = blockIdx.x * 4 + wid;
    if (row >= NN) return;
    const float* xr = xs + (size_t)row * 128;
    float v0 = xr[lane], v1 = xr[lane + 64];
    float s0 = v0 * att_src[lane], s1 = v1 * att_src[64 + lane];
    float d0 = v0 * att_dst[lane], d1 = v1 * att_dst[64 + lane];
    for (int off = 1; off < 16; off <<= 1) {
        s0 += __shfl_xor(s0, off, 64); s1 += __shfl_xor(s1, off, 64);
        d0 += __shfl_xor(d0, off, 64); d1 += __shfl_xor(d1, off, 64);
    }
    if ((lane & 15) == 0) {
        int h = lane >> 4;
        a_src[row * 8 + h] = s0;     a_src[row * 8 + 4 + h] = s1;
        a_dst[row * 8 + h] = d0;     a_dst[row * 8 + 4 + h] = d1;
    }
}

// ---------------------------------------------------------------------------
// edge-parallel attention weights in CSR order: w[pos*8+h] = exp(lrelu(...))
// ---------------------------------------------------------------------------
__global__ void k_weights(const int* __restrict__ srt_src, const int* __restrict__ srt_dst,
                          const int* __restrict__ srt_eid,
                          const float* __restrict__ ae, const float* __restrict__ a_src,
                          const float* __restrict__ a_dst, float* __restrict__ w) {
    int pos = blockIdx.x * 256 + threadIdx.x;
    if (pos >= EE) return;
    int s = srt_src[pos], d = srt_dst[pos], eid = srt_eid[pos];
    const float* as = a_src + (size_t)s * 8;
    const float* ad = a_dst + (size_t)d * 8;
    const float* av = ae + (size_t)eid * 8;
    float4 s0 = *(const float4*)as, s1 = *(const float4*)(as + 4);
    float4 d0 = *(const float4*)ad, d1 = *(const float4*)(ad + 4);
    float4 e0 = *(const float4*)av, e1 = *(const float4*)(av + 4);
    float al[8] = {s0.x + d0.x + e0.x, s0.y + d0.y + e0.y, s0.z + d0.z + e0.z, s0.w + d0.w + e0.w,
                   s1.x + d1.x + e1.x, s1.y + d1.y + e1.y, s1.z + d1.z + e1.z, s1.w + d1.w + e1.w};
    float o[8];
    #pragma unroll
    for (int h = 0; h < 8; ++h) {
        float a = al[h];
        a = a > 0.f ? a : 0.2f * a;
        o[h] = __expf(a);
    }
    float* wp = w + (size_t)pos * 8;
    *(float4*)wp = make_float4(o[0], o[1], o[2], o[3]);
    *(float4*)(wp + 4) = make_float4(o[4], o[5], o[6], o[7]);
}

// ---------------------------------------------------------------------------
// aggregation (precomputed weights) + bias + ELU + residual + LayerNorm
// one 128-thread block per destination node; 2-deep pipelined gather
// ---------------------------------------------------------------------------
__global__ void k_agg(const int* __restrict__ rowptr, const int* __restrict__ srt_src,
                      const float* __restrict__ w,
                      const float* __restrict__ a_src, const float* __restrict__ a_dst,
                      const float* __restrict__ se,
                      const float* __restrict__ xs, const float* __restrict__ res,
                      const float* __restrict__ bias, const float* __restrict__ gamma,
                      const float* __restrict__ beta, float* __restrict__ outh) {
    int i = blockIdx.x;
    int t = threadIdx.x;  // 128
    int h = t >> 4;
    int b = rowptr[i], en = rowptr[i + 1];
    float acc = 0.f, denom = 0.f;
    int s0 = 0, s1 = 0;
    float w0 = 0.f, w1 = 0.f, x0 = 0.f;
    if (b < en)     { s0 = srt_src[b];     w0 = w[(size_t)b * 8 + h]; }
    if (b + 1 < en) { s1 = srt_src[b + 1]; w1 = w[(size_t)(b + 1) * 8 + h]; }
    if (b < en) x0 = xs[(size_t)s0 * 128 + t];
    for (int e = b; e < en; ++e) {
        float xc = x0, wc = w0;
        s0 = s1; w0 = w1;
        if (e + 1 < en) x0 = xs[(size_t)s0 * 128 + t];
        if (e + 2 < en) { s1 = srt_src[e + 2]; w1 = w[(size_t)(e + 2) * 8 + h]; }
        acc += wc * xc;
        denom += wc;
    }
    {   // self loop (mean edge-attr folded to se[h])
        float al = a_src[i * 8 + h] + a_dst[i * 8 + h] + se[h];
        al = al > 0.f ? al : 0.2f * al;
        float wv = __expf(al);
        denom += wv;
        acc += wv * xs[(size_t)i * 128 + t];
    }
    float val = acc / (denom + 1e-16f);
    val += bias[t];
    val = val > 0.f ? val : (__expf(val) - 1.f);            // ELU
    val += res[(size_t)i * 128 + t];                        // residual
    // LayerNorm over 128 features
    float s = val, q = val * val;
    for (int off = 1; off < 64; off <<= 1) { s += __shfl_xor(s, off, 64); q += __shfl_xor(q, off, 64); }
    __shared__ float s2[2], q2[2];
    if ((t & 63) == 0) { s2[t >> 6] = s; q2[t >> 6] = q; }
    __syncthreads();
    float mu = (s2[0] + s2[1]) * (1.f / 128.f);
    float var = (q2[0] + q2[1]) * (1.f / 128.f) - mu * mu;
    float r = rsqrtf(var + 1e-5f);
    outh[(size_t)i * 128 + t] = (val - mu) * r * gamma[t] + beta[t];
}

// ---------------------------------------------------------------------------
extern "C" void kernel_launch(void* const* d_in, const int* in_sizes, int n_in,
                              void* d_out, int out_size, void* d_ws, size_t ws_size,
                              hipStream_t stream) {
    const float* x        = (const float*)d_in[0];
    const int*   ei       = (const int*)d_in[1];
    const float* enc_w1   = (const float*)d_in[2];
    const float* enc_b1   = (const float*)d_in[3];
    const float* enc_w2   = (const float*)d_in[4];
    const float* enc_b2   = (const float*)d_in[5];
    const float* in_w     = (const float*)d_in[6];
    const float* in_b     = (const float*)d_in[7];
    const float* lin_w1   = (const float*)d_in[8];
    const float* att_src1 = (const float*)d_in[9];
    const float* att_dst1 = (const float*)d_in[10];
    const float* att_edge1= (const float*)d_in[11];
    const float* lin_ew1  = (const float*)d_in[12];
    const float* bias1    = (const float*)d_in[13];
    const float* lin_w2   = (const float*)d_in[14];
    const float* att_src2 = (const float*)d_in[15];
    const float* att_dst2 = (const float*)d_in[16];
    const float* att_edge2= (const float*)d_in[17];
    const float* lin_ew2  = (const float*)d_in[18];
    const float* bias2    = (const float*)d_in[19];
    const float* g1       = (const float*)d_in[20];
    const float* bn1      = (const float*)d_in[21];
    const float* g2       = (const float*)d_in[22];
    const float* bn2      = (const float*)d_in[23];
    const float* jk_w     = (const float*)d_in[24];
    const float* jk_b     = (const float*)d_in[25];
    float* out = (float*)d_out;

    char* wsp = (char*)d_ws;
    size_t off = 0;
    auto alloc = [&](size_t bytes) -> char* {
        char* p = wsp + off;
        off += (bytes + 255) & ~(size_t)255;
        return p;
    };
    float* h0    = (float*)alloc(sizeof(float) * (size_t)NN * 128);
    float* h1    = (float*)alloc(sizeof(float) * (size_t)NN * 128);
    float* h2    = (float*)alloc(sizeof(float) * (size_t)NN * 128);
    float* xs    = (float*)alloc(sizeof(float) * (size_t)NN * 128);
    float* ae1   = (float*)alloc(sizeof(float) * (size_t)EE * 8);
    float* ae2   = (float*)alloc(sizeof(float) * (size_t)EE * 8);
    float* wbuf  = (float*)alloc(sizeof(float) * (size_t)EE * 8);
    float* norms = (float*)alloc(sizeof(float) * NN);
    float* a_src1= (float*)alloc(sizeof(float) * NN * 8);
    float* a_dst1= (float*)alloc(sizeof(float) * NN * 8);
    float* a_src2= (float*)alloc(sizeof(float) * NN * 8);
    float* a_dst2= (float*)alloc(sizeof(float) * NN * 8);
    float* P1    = (float*)alloc(sizeof(float) * 128);
    float* q1    = (float*)alloc(sizeof(float) * 8);
    float* P2    = (float*)alloc(sizeof(float) * 128);
    float* q2    = (float*)alloc(sizeof(float) * 8);
    float* se1   = (float*)alloc(sizeof(float) * 8);
    float* se2   = (float*)alloc(sizeof(float) * 8);
    float* sums  = (float*)alloc(sizeof(float) * 16);
    int* deg     = (int*)alloc(sizeof(int) * NN);
    int* rowptr  = (int*)alloc(sizeof(int) * (NN + 1));
    int* cursor  = (int*)alloc(sizeof(int) * NN);
    int* srt_src = (int*)alloc(sizeof(int) * EE);
    int* srt_eid = (int*)alloc(sizeof(int) * EE);
    int* srt_dst = (int*)alloc(sizeof(int) * EE);
    (void)ws_size; (void)in_sizes; (void)n_in; (void)out_size;

    hipMemsetAsync(sums, 0, 16 * sizeof(float), stream);
    hipMemsetAsync(deg, 0, NN * sizeof(int), stream);

    k_precompute<<<1, 128, 0, stream>>>(lin_ew1, att_edge1, lin_ew2, att_edge2, enc_w2, enc_b2,
                                        P1, q1, P2, q2);
    k_norms<<<(NN + 3) / 4, 256, 0, stream>>>(x, norms);
    k_encoder<<<(EE + 15) / 16, 256, 0, stream>>>(x, ei, norms, enc_w1, enc_b1,
                                                  P1, q1, P2, q2, ae1, ae2);
    k_redsum<<<128, 256, 0, stream>>>(ae1, ae2, sums);
    k_selfedge<<<1, 64, 0, stream>>>(sums, se1, se2);
    k_hist<<<(EE + 255) / 256, 256, 0, stream>>>(ei, deg);
    k_scan<<<1, 1024, 0, stream>>>(deg, rowptr, cursor);
    k_scatter<<<(EE + 255) / 256, 256, 0, stream>>>(ei, cursor, srt_src, srt_eid, srt_dst);

    dim3 gg((NN + 63) / 64, 2);
    k_gemm<true ><<<gg, 256, 0, stream>>>(x,  in_w,   128, in_b,    h0, NN);
    k_gemm<false><<<gg, 256, 0, stream>>>(x,  lin_w1, 128, nullptr, xs, NN);
    k_att<<<(NN + 3) / 4, 256, 0, stream>>>(xs, att_src1, att_dst1, a_src1, a_dst1);
    k_weights<<<(EE + 255) / 256, 256, 0, stream>>>(srt_src, srt_dst, srt_eid, ae1,
                                                    a_src1, a_dst1, wbuf);
    k_agg<<<NN, 128, 0, stream>>>(rowptr, srt_src, wbuf, a_src1, a_dst1, se1,
                                  xs, h0, bias1, g1, bn1, h1);
    k_gemm<false><<<gg, 256, 0, stream>>>(h1, lin_w2, 128, nullptr, xs, NN);
    k_att<<<(NN + 3) / 4, 256, 0, stream>>>(xs, att_src2, att_dst2, a_src2, a_dst2);
    k_weights<<<(EE + 255) / 256, 256, 0, stream>>>(srt_src, srt_dst, srt_eid, ae2,
                                                    a_src2, a_dst2, wbuf);
    k_agg<<<NN, 128, 0, stream>>>(rowptr, srt_src, wbuf, a_src2, a_dst2, se2,
                                  xs, h1, bias2, g2, bn2, h2);
    k_gemm_jk<<<gg, 256, 0, stream>>>(h0, h1, h2, jk_w, jk_b, out, NN);
}

// Round 4
// 604.367 us; speedup vs baseline: 4.3090x; 1.2847x over previous
//
#include <hip/hip_runtime.h>

#define NN 50000
#define EE 600000
#define FF 128
#define HH 8
#define CC 16
#define DD 128

typedef unsigned short u16;
typedef short bf8 __attribute__((ext_vector_type(8)));
typedef float f4 __attribute__((ext_vector_type(4)));

static __device__ __forceinline__ float b2f(u16 u) {
    union { float f; unsigned i; } v; v.i = (unsigned)u << 16; return v.f;
}
static __device__ __forceinline__ u16 f2b(float f) {
    union { float f; unsigned i; } v; v.f = f;
    unsigned r = v.i + 0x7fff + ((v.i >> 16) & 1);
    return (u16)(r >> 16);
}
static __device__ __forceinline__ void unpack8(uint4 v, float* o) {
    o[0] = b2f((u16)(v.x & 0xffff)); o[1] = b2f((u16)(v.x >> 16));
    o[2] = b2f((u16)(v.y & 0xffff)); o[3] = b2f((u16)(v.y >> 16));
    o[4] = b2f((u16)(v.z & 0xffff)); o[5] = b2f((u16)(v.w & 0xffff));
    o[5] = b2f((u16)(v.z >> 16));    o[6] = b2f((u16)(v.w & 0xffff));
    o[7] = b2f((u16)(v.w >> 16));
}
// LDS tile swizzle: tile is [128 rows][128 bf16]; 16B-unit index with XOR
static __device__ __forceinline__ int tswz(int row, int u) {
    return (row * 16 + (u ^ (row & 7))) * 8;   // u16 element index
}

// ---------------------------------------------------------------------------
// fp32 -> bf16 bulk convert
// ---------------------------------------------------------------------------
__global__ void k_cvt(const float* __restrict__ src, u16* __restrict__ dst, int n) {
    int i = (blockIdx.x * 256 + threadIdx.x) * 8;
    if (i + 8 <= n) {
        float4 v0 = *(const float4*)(src + i);
        float4 v1 = *(const float4*)(src + i + 4);
        u16 o[8] = {f2b(v0.x), f2b(v0.y), f2b(v0.z), f2b(v0.w),
                    f2b(v1.x), f2b(v1.y), f2b(v1.z), f2b(v1.w)};
        *(uint4*)(dst + i) = *(uint4*)o;
    } else {
        for (int j = i; j < n; ++j) dst[j] = f2b(src[j]);
    }
}

// ---------------------------------------------------------------------------
// K0: fold lin_edge_w + att_edge into M[8][8]; fold encoder layer-2 through M
// ---------------------------------------------------------------------------
__global__ void k_precompute(const float* __restrict__ lew1, const float* __restrict__ ae1,
                             const float* __restrict__ lew2, const float* __restrict__ ae2,
                             const float* __restrict__ enc_w2, const float* __restrict__ enc_b2,
                             float* __restrict__ P1, float* __restrict__ q1,
                             float* __restrict__ P2, float* __restrict__ q2) {
    __shared__ float sM1[64], sM2[64];
    int t = threadIdx.x;  // 128 threads
    {
        int kk = (t & 63) >> 3, h = t & 7;
        const float* lew = (t < 64) ? lew1 : lew2;
        const float* ae  = (t < 64) ? ae1  : ae2;
        float s = 0.f;
        for (int c = 0; c < 16; ++c) s += lew[(h * 16 + c) * 8 + kk] * ae[h * 16 + c];
        if (t < 64) sM1[kk * 8 + h] = s; else sM2[kk * 8 + h] = s;
    }
    __syncthreads();
    int c = t >> 3, h = t & 7;
    float p1 = 0.f, p2 = 0.f;
    for (int k = 0; k < 8; ++k) {
        float w = enc_w2[k * 16 + c];
        p1 += w * sM1[k * 8 + h];
        p2 += w * sM2[k * 8 + h];
    }
    P1[c * 8 + h] = p1;
    P2[c * 8 + h] = p2;
    if (t < 8) {
        float s1 = 0.f, s2 = 0.f;
        for (int k = 0; k < 8; ++k) { float b = enc_b2[k]; s1 += b * sM1[k * 8 + t]; s2 += b * sM2[k * 8 + t]; }
        q1[t] = s1; q2[t] = s2;
    }
}

// ---------------------------------------------------------------------------
// K1: node squared norms (fp32 x for accuracy)
// ---------------------------------------------------------------------------
__global__ void k_norms(const float* __restrict__ x, float* __restrict__ norms) {
    int wid = threadIdx.x >> 6, lane = threadIdx.x & 63;
    int row = blockIdx.x * 4 + wid;
    if (row >= NN) return;
    const float* xr = x + (size_t)row * FF;
    float a = xr[lane], b = xr[lane + 64];
    float s = a * a + b * b;
    for (int off = 1; off < 64; off <<= 1) s += __shfl_xor(s, off, 64);
    if (lane == 0) norms[row] = s;
}

// ---------------------------------------------------------------------------
// K2: edge encoder, 16 lanes per edge, bf16 x gather (halved bytes)
// ---------------------------------------------------------------------------
__global__ void k_encoder(const u16* __restrict__ xb, const int* __restrict__ ei,
                          const float* __restrict__ norms,
                          const float* __restrict__ enc_w1, const float* __restrict__ enc_b1,
                          const float* __restrict__ P1, const float* __restrict__ q1,
                          const float* __restrict__ P2, const float* __restrict__ q2,
                          float* __restrict__ ae1out, float* __restrict__ ae2out) {
    __shared__ float sA[16], sB[16], sC[16], sb[16];
    __shared__ float sP[256], sq[16];
    __shared__ float hidbuf[16][17];
    int t = threadIdx.x;
    if (t < 16) {
        float w0 = enc_w1[t * 4 + 0], w1 = enc_w1[t * 4 + 1];
        float w2 = enc_w1[t * 4 + 2], w3 = enc_w1[t * 4 + 3];
        sA[t] = w0 - 2.f * w1;
        sB[t] = w1 + w2;
        sC[t] = w1 + w3;
        sb[t] = enc_b1[t];
    }
    if (t < 128) sP[t] = P1[t]; else if (t < 256) sP[t] = P2[t - 128];
    if (t >= 16 && t < 24) sq[t - 16] = q1[t - 16];
    if (t >= 24 && t < 32) sq[t - 16] = q2[t - 24];
    __syncthreads();
    int eq = t >> 4, l = t & 15;
    int e = blockIdx.x * 16 + eq;
    if (e >= EE) return;
    int s_ = ei[e], d_ = ei[EE + e];
    uint4 av = *(const uint4*)(xb + (size_t)s_ * FF + l * 8);
    uint4 bv = *(const uint4*)(xb + (size_t)d_ * FF + l * 8);
    float af[8], bf[8];
    af[0] = b2f((u16)(av.x & 0xffff)); af[1] = b2f((u16)(av.x >> 16));
    af[2] = b2f((u16)(av.y & 0xffff)); af[3] = b2f((u16)(av.y >> 16));
    af[4] = b2f((u16)(av.z & 0xffff)); af[5] = b2f((u16)(av.z >> 16));
    af[6] = b2f((u16)(av.w & 0xffff)); af[7] = b2f((u16)(av.w >> 16));
    bf[0] = b2f((u16)(bv.x & 0xffff)); bf[1] = b2f((u16)(bv.x >> 16));
    bf[2] = b2f((u16)(bv.y & 0xffff)); bf[3] = b2f((u16)(bv.y >> 16));
    bf[4] = b2f((u16)(bv.z & 0xffff)); bf[5] = b2f((u16)(bv.z >> 16));
    bf[6] = b2f((u16)(bv.w & 0xffff)); bf[7] = b2f((u16)(bv.w >> 16));
    float dot = 0.f;
    #pragma unroll
    for (int j = 0; j < 8; ++j) dot += af[j] * bf[j];
    #pragma unroll
    for (int off = 1; off < 16; off <<= 1) dot += __shfl_xor(dot, off, 64);
    float ni = norms[s_], nj = norms[d_];
    float v = sA[l] * dot + sB[l] * ni + sC[l] * nj + sb[l];
    hidbuf[eq][l] = v > 0.f ? v : 0.f;
    int conv = l >> 3, h = l & 7;
    const float* P = sP + conv * 128;
    float a = sq[conv * 8 + h];
    #pragma unroll
    for (int c = 0; c < 16; ++c) a += hidbuf[eq][c] * P[c * 8 + h];
    if (conv == 0) ae1out[(size_t)e * 8 + h] = a;
    else           ae2out[(size_t)e * 8 + h] = a;
}

// ---------------------------------------------------------------------------
// K2b: grid-stride reduction of ae1/ae2 per head -> sums[16]
// ---------------------------------------------------------------------------
__global__ void k_redsum(const float* __restrict__ a1, const float* __restrict__ a2,
                         float* __restrict__ sums) {
    int tid = threadIdx.x;  // 256
    int gid = blockIdx.x * 256 + tid;
    int stride = gridDim.x * 256;
    float s1 = 0.f, s2 = 0.f;
    for (int i = gid; i < EE * 8; i += stride) { s1 += a1[i]; s2 += a2[i]; }
    for (int off = 8; off < 64; off <<= 1) { s1 += __shfl_xor(s1, off, 64); s2 += __shfl_xor(s2, off, 64); }
    __shared__ float b1[4][8], b2[4][8];
    int wid = tid >> 6, lane = tid & 63;
    if (lane < 8) { b1[wid][lane] = s1; b2[wid][lane] = s2; }
    __syncthreads();
    if (tid < 8) {
        float t1 = b1[0][tid] + b1[1][tid] + b1[2][tid] + b1[3][tid];
        float t2 = b2[0][tid] + b2[1][tid] + b2[2][tid] + b2[3][tid];
        atomicAdd(&sums[tid], t1);
        atomicAdd(&sums[8 + tid], t2);
    }
}

__global__ void k_selfedge(const float* __restrict__ sums, float* __restrict__ se1, float* __restrict__ se2) {
    int t = threadIdx.x;
    if (t < 8) se1[t] = sums[t] * (1.f / (float)EE);
    else if (t < 16) se2[t - 8] = sums[t] * (1.f / (float)EE);
}

// ---------------------------------------------------------------------------
// CSR build by dst
// ---------------------------------------------------------------------------
__global__ void k_hist(const int* __restrict__ ei, int* __restrict__ deg) {
    int e = blockIdx.x * 256 + threadIdx.x;
    if (e < EE) atomicAdd(&deg[ei[EE + e]], 1);
}

__global__ void k_scan(const int* __restrict__ deg, int* __restrict__ rowptr, int* __restrict__ cursor) {
    __shared__ int wsum[16];
    __shared__ int carry;
    int t = threadIdx.x, wid = t >> 6, lane = t & 63;
    if (t == 0) carry = 0;
    __syncthreads();
    for (int base = 0; base < NN; base += 1024) {
        int v = (base + t < NN) ? deg[base + t] : 0;
        int sc = v;
        #pragma unroll
        for (int off = 1; off < 64; off <<= 1) { int n = __shfl_up(sc, off, 64); if (lane >= off) sc += n; }
        if (lane == 63) wsum[wid] = sc;
        __syncthreads();
        if (t < 16) {
            int ws = wsum[t];
            #pragma unroll
            for (int off = 1; off < 16; off <<= 1) { int n = __shfl_up(ws, off, 64); if (t >= off) ws += n; }
            wsum[t] = ws;
        }
        __syncthreads();
        int ex = carry + (wid ? wsum[wid - 1] : 0) + sc - v;
        if (base + t < NN) { rowptr[base + t] = ex; cursor[base + t] = ex; }
        __syncthreads();
        if (t == 0) carry += wsum[15];
        __syncthreads();
    }
    if (t == 0) rowptr[NN] = carry;
}

__global__ void k_scatter(const int* __restrict__ ei, int* __restrict__ cursor,
                          int* __restrict__ srt_src, int* __restrict__ srt_eid,
                          int* __restrict__ srt_dst) {
    int e = blockIdx.x * 256 + threadIdx.x;
    if (e < EE) {
        int d = ei[EE + e];
        int pos = atomicAdd(&cursor[d], 1);
        srt_src[pos] = ei[e];
        srt_eid[pos] = e;
        srt_dst[pos] = d;
    }
}

// ---------------------------------------------------------------------------
// bf16 MFMA GEMM: out_bf16[N,128] = X_bf[N,128] @ W_bf^T (+bias)
// BM=128, 4 waves, each wave 32 rows x 128 cols. K=128 staged once.
// ---------------------------------------------------------------------------
template <bool BIAS>
__global__ __launch_bounds__(256, 2) void k_mfma(const u16* __restrict__ X,
                                                 const u16* __restrict__ W,
                                                 const float* __restrict__ bias,
                                                 u16* __restrict__ out, int nrows) {
    __shared__ __align__(16) u16 tA[128 * 128];
    __shared__ __align__(16) u16 tB[128 * 128];
    int t = threadIdx.x;
    int r0 = blockIdx.x * 128;
    #pragma unroll
    for (int it = 0; it < 8; ++it) {
        int idx = it * 256 + t;
        int r = idx >> 4, u = idx & 15;
        uint4 v = make_uint4(0u, 0u, 0u, 0u);
        if (r0 + r < nrows) v = *(const uint4*)(X + (size_t)(r0 + r) * 128 + u * 8);
        *(uint4*)&tA[tswz(r, u)] = v;
        uint4 wv = *(const uint4*)(W + (size_t)r * 128 + u * 8);
        *(uint4*)&tB[tswz(r, u)] = wv;
    }
    __syncthreads();
    int l = t & 63, w = t >> 6;
    int lr = l & 15, lk = l >> 4;
    f4 acc[2][8];
    #pragma unroll
    for (int m = 0; m < 2; ++m)
        #pragma unroll
        for (int n = 0; n < 8; ++n) acc[m][n] = (f4){0.f, 0.f, 0.f, 0.f};
    #pragma unroll
    for (int s = 0; s < 4; ++s) {
        int u = s * 4 + lk;
        bf8 a0 = *(bf8*)&tA[tswz(w * 32 + lr, u)];
        bf8 a1 = *(bf8*)&tA[tswz(w * 32 + 16 + lr, u)];
        #pragma unroll
        for (int n = 0; n < 8; ++n) {
            bf8 b = *(bf8*)&tB[tswz(n * 16 + lr, u)];
            acc[0][n] = __builtin_amdgcn_mfma_f32_16x16x32_bf16(a0, b, acc[0][n], 0, 0, 0);
            acc[1][n] = __builtin_amdgcn_mfma_f32_16x16x32_bf16(a1, b, acc[1][n], 0, 0, 0);
        }
    }
    #pragma unroll
    for (int n = 0; n < 8; ++n) {
        int col = n * 16 + lr;
        float bv = BIAS ? bias[col] : 0.f;
        #pragma unroll
        for (int m = 0; m < 2; ++m) {
            #pragma unroll
            for (int g = 0; g < 4; ++g) {
                int row = r0 + w * 32 + m * 16 + lk * 4 + g;
                if (row < nrows) out[(size_t)row * 128 + col] = f2b(acc[m][n][g] + bv);
            }
        }
    }
}

// ---------------------------------------------------------------------------
// fused JK MFMA GEMM: out_f32 = [h0 h1 h2]_bf @ jk_w_bf^T + jk_b (K=384)
// ---------------------------------------------------------------------------
__global__ __launch_bounds__(256, 2) void k_mfma_jk(const u16* __restrict__ h0,
                                                    const u16* __restrict__ h1,
                                                    const u16* __restrict__ h2,
                                                    const u16* __restrict__ W,
                                                    const float* __restrict__ bias,
                                                    float* __restrict__ out, int nrows) {
    __shared__ __align__(16) u16 tA[128 * 128];
    __shared__ __align__(16) u16 tB[128 * 128];
    int t = threadIdx.x;
    int r0 = blockIdx.x * 128;
    int l = t & 63, w = t >> 6;
    int lr = l & 15, lk = l >> 4;
    f4 acc[2][8];
    #pragma unroll
    for (int m = 0; m < 2; ++m)
        #pragma unroll
        for (int n = 0; n < 8; ++n) acc[m][n] = (f4){0.f, 0.f, 0.f, 0.f};
    for (int seg = 0; seg < 3; ++seg) {
        if (seg) __syncthreads();
        const u16* X = seg == 0 ? h0 : (seg == 1 ? h1 : h2);
        #pragma unroll
        for (int it = 0; it < 8; ++it) {
            int idx = it * 256 + t;
            int r = idx >> 4, u = idx & 15;
            uint4 v = make_uint4(0u, 0u, 0u, 0u);
            if (r0 + r < nrows) v = *(const uint4*)(X + (size_t)(r0 + r) * 128 + u * 8);
            *(uint4*)&tA[tswz(r, u)] = v;
            uint4 wv = *(const uint4*)(W + (size_t)r * 384 + seg * 128 + u * 8);
            *(uint4*)&tB[tswz(r, u)] = wv;
        }
        __syncthreads();
        #pragma unroll
        for (int s = 0; s < 4; ++s) {
            int u = s * 4 + lk;
            bf8 a0 = *(bf8*)&tA[tswz(w * 32 + lr, u)];
            bf8 a1 = *(bf8*)&tA[tswz(w * 32 + 16 + lr, u)];
            #pragma unroll
            for (int n = 0; n < 8; ++n) {
                bf8 b = *(bf8*)&tB[tswz(n * 16 + lr, u)];
                acc[0][n] = __builtin_amdgcn_mfma_f32_16x16x32_bf16(a0, b, acc[0][n], 0, 0, 0);
                acc[1][n] = __builtin_amdgcn_mfma_f32_16x16x32_bf16(a1, b, acc[1][n], 0, 0, 0);
            }
        }
    }
    #pragma unroll
    for (int n = 0; n < 8; ++n) {
        int col = n * 16 + lr;
        float bv = bias[col];
        #pragma unroll
        for (int m = 0; m < 2; ++m) {
            #pragma unroll
            for (int g = 0; g < 4; ++g) {
                int row = r0 + w * 32 + m * 16 + lk * 4 + g;
                if (row < nrows) out[(size_t)row * 128 + col] = acc[m][n][g] + bv;
            }
        }
    }
}

// ---------------------------------------------------------------------------
// per-node attention scores a_src/a_dst (wave per row, bf16 xs)
// ---------------------------------------------------------------------------
__global__ void k_att(const u16* __restrict__ xs, const float* __restrict__ att_src,
                      const float* __restrict__ att_dst,
                      float* __restrict__ a_src, float* __restrict__ a_dst) {
    int wid = threadIdx.x >> 6, lane = threadIdx.x & 63;
    int row = blockIdx.x * 4 + wid;
    if (row >= NN) return;
    const u16* xr = xs + (size_t)row * 128;
    float v0 = b2f(xr[lane]), v1 = b2f(xr[lane + 64]);
    float s0 = v0 * att_src[lane], s1 = v1 * att_src[64 + lane];
    float d0 = v0 * att_dst[lane], d1 = v1 * att_dst[64 + lane];
    for (int off = 1; off < 16; off <<= 1) {
        s0 += __shfl_xor(s0, off, 64); s1 += __shfl_xor(s1, off, 64);
        d0 += __shfl_xor(d0, off, 64); d1 += __shfl_xor(d1, off, 64);
    }
    if ((lane & 15) == 0) {
        int h = lane >> 4;
        a_src[row * 8 + h] = s0;     a_src[row * 8 + 4 + h] = s1;
        a_dst[row * 8 + h] = d0;     a_dst[row * 8 + 4 + h] = d1;
    }
}

// ---------------------------------------------------------------------------
// edge-parallel attention weights in CSR order
// ---------------------------------------------------------------------------
__global__ void k_weights(const int* __restrict__ srt_src, const int* __restrict__ srt_dst,
                          const int* __restrict__ srt_eid,
                          const float* __restrict__ ae, const float* __restrict__ a_src,
                          const float* __restrict__ a_dst, float* __restrict__ w) {
    int pos = blockIdx.x * 256 + threadIdx.x;
    if (pos >= EE) return;
    int s = srt_src[pos], d = srt_dst[pos], eid = srt_eid[pos];
    const float* as = a_src + (size_t)s * 8;
    const float* ad = a_dst + (size_t)d * 8;
    const float* av = ae + (size_t)eid * 8;
    float4 s0 = *(const float4*)as, s1 = *(const float4*)(as + 4);
    float4 d0 = *(const float4*)ad, d1 = *(const float4*)(ad + 4);
    float4 e0 = *(const float4*)av, e1 = *(const float4*)(av + 4);
    float al[8] = {s0.x + d0.x + e0.x, s0.y + d0.y + e0.y, s0.z + d0.z + e0.z, s0.w + d0.w + e0.w,
                   s1.x + d1.x + e1.x, s1.y + d1.y + e1.y, s1.z + d1.z + e1.z, s1.w + d1.w + e1.w};
    float o[8];
    #pragma unroll
    for (int h = 0; h < 8; ++h) {
        float a = al[h];
        a = a > 0.f ? a : 0.2f * a;
        o[h] = __expf(a);
    }
    float* wp = w + (size_t)pos * 8;
    *(float4*)wp = make_float4(o[0], o[1], o[2], o[3]);
    *(float4*)(wp + 4) = make_float4(o[4], o[5], o[6], o[7]);
}

// ---------------------------------------------------------------------------
// aggregation + bias + ELU + residual + LayerNorm (bf16 xs/res/out)
// ---------------------------------------------------------------------------
__global__ void k_agg(const int* __restrict__ rowptr, const int* __restrict__ srt_src,
                      const float* __restrict__ w,
                      const float* __restrict__ a_src, const float* __restrict__ a_dst,
                      const float* __restrict__ se,
                      const u16* __restrict__ xs, const u16* __restrict__ res,
                      const float* __restrict__ bias, const float* __restrict__ gamma,
                      const float* __restrict__ beta, u16* __restrict__ outh) {
    int i = blockIdx.x;
    int t = threadIdx.x;  // 128
    int h = t >> 4;
    int b = rowptr[i], en = rowptr[i + 1];
    float acc = 0.f, denom = 0.f;
    int s0 = 0, s1 = 0;
    float w0 = 0.f, w1 = 0.f, x0 = 0.f;
    if (b < en)     { s0 = srt_src[b];     w0 = w[(size_t)b * 8 + h]; }
    if (b + 1 < en) { s1 = srt_src[b + 1]; w1 = w[(size_t)(b + 1) * 8 + h]; }
    if (b < en) x0 = b2f(xs[(size_t)s0 * 128 + t]);
    for (int e = b; e < en; ++e) {
        float xc = x0, wc = w0;
        s0 = s1; w0 = w1;
        if (e + 1 < en) x0 = b2f(xs[(size_t)s0 * 128 + t]);
        if (e + 2 < en) { s1 = srt_src[e + 2]; w1 = w[(size_t)(e + 2) * 8 + h]; }
        acc += wc * xc;
        denom += wc;
    }
    {   // self loop
        float al = a_src[i * 8 + h] + a_dst[i * 8 + h] + se[h];
        al = al > 0.f ? al : 0.2f * al;
        float wv = __expf(al);
        denom += wv;
        acc += wv * b2f(xs[(size_t)i * 128 + t]);
    }
    float val = acc / (denom + 1e-16f);
    val += bias[t];
    val = val > 0.f ? val : (__expf(val) - 1.f);            // ELU
    val += b2f(res[(size_t)i * 128 + t]);                   // residual
    float s = val, q = val * val;
    for (int off = 1; off < 64; off <<= 1) { s += __shfl_xor(s, off, 64); q += __shfl_xor(q, off, 64); }
    __shared__ float s2[2], q2[2];
    if ((t & 63) == 0) { s2[t >> 6] = s; q2[t >> 6] = q; }
    __syncthreads();
    float mu = (s2[0] + s2[1]) * (1.f / 128.f);
    float var = (q2[0] + q2[1]) * (1.f / 128.f) - mu * mu;
    float r = rsqrtf(var + 1e-5f);
    outh[(size_t)i * 128 + t] = f2b((val - mu) * r * gamma[t] + beta[t]);
}

// ---------------------------------------------------------------------------
extern "C" void kernel_launch(void* const* d_in, const int* in_sizes, int n_in,
                              void* d_out, int out_size, void* d_ws, size_t ws_size,
                              hipStream_t stream) {
    const float* x        = (const float*)d_in[0];
    const int*   ei       = (const int*)d_in[1];
    const float* enc_w1   = (const float*)d_in[2];
    const float* enc_b1   = (const float*)d_in[3];
    const float* enc_w2   = (const float*)d_in[4];
    const float* enc_b2   = (const float*)d_in[5];
    const float* in_w     = (const float*)d_in[6];
    const float* in_b     = (const float*)d_in[7];
    const float* lin_w1   = (const float*)d_in[8];
    const float* att_src1 = (const float*)d_in[9];
    const float* att_dst1 = (const float*)d_in[10];
    const float* att_edge1= (const float*)d_in[11];
    const float* lin_ew1  = (const float*)d_in[12];
    const float* bias1    = (const float*)d_in[13];
    const float* lin_w2   = (const float*)d_in[14];
    const float* att_src2 = (const float*)d_in[15];
    const float* att_dst2 = (const float*)d_in[16];
    const float* att_edge2= (const float*)d_in[17];
    const float* lin_ew2  = (const float*)d_in[18];
    const float* bias2    = (const float*)d_in[19];
    const float* g1       = (const float*)d_in[20];
    const float* bn1      = (const float*)d_in[21];
    const float* g2       = (const float*)d_in[22];
    const float* bn2      = (const float*)d_in[23];
    const float* jk_w     = (const float*)d_in[24];
    const float* jk_b     = (const float*)d_in[25];
    float* out = (float*)d_out;

    char* wsp = (char*)d_ws;
    size_t off = 0;
    auto alloc = [&](size_t bytes) -> char* {
        char* p = wsp + off;
        off += (bytes + 255) & ~(size_t)255;
        return p;
    };
    u16* x_bf   = (u16*)alloc(sizeof(u16) * (size_t)NN * 128);
    u16* h0b    = (u16*)alloc(sizeof(u16) * (size_t)NN * 128);
    u16* h1b    = (u16*)alloc(sizeof(u16) * (size_t)NN * 128);
    u16* h2b    = (u16*)alloc(sizeof(u16) * (size_t)NN * 128);
    u16* xsb    = (u16*)alloc(sizeof(u16) * (size_t)NN * 128);
    u16* inw_b  = (u16*)alloc(sizeof(u16) * 16384);
    u16* w1_b   = (u16*)alloc(sizeof(u16) * 16384);
    u16* w2_b   = (u16*)alloc(sizeof(u16) * 16384);
    u16* jkw_b  = (u16*)alloc(sizeof(u16) * 49152);
    float* ae1   = (float*)alloc(sizeof(float) * (size_t)EE * 8);
    float* ae2   = (float*)alloc(sizeof(float) * (size_t)EE * 8);
    float* wbuf  = (float*)alloc(sizeof(float) * (size_t)EE * 8);
    float* norms = (float*)alloc(sizeof(float) * NN);
    float* a_src1= (float*)alloc(sizeof(float) * NN * 8);
    float* a_dst1= (float*)alloc(sizeof(float) * NN * 8);
    float* a_src2= (float*)alloc(sizeof(float) * NN * 8);
    float* a_dst2= (float*)alloc(sizeof(float) * NN * 8);
    float* P1    = (float*)alloc(sizeof(float) * 128);
    float* q1    = (float*)alloc(sizeof(float) * 8);
    float* P2    = (float*)alloc(sizeof(float) * 128);
    float* q2    = (float*)alloc(sizeof(float) * 8);
    float* se1   = (float*)alloc(sizeof(float) * 8);
    float* se2   = (float*)alloc(sizeof(float) * 8);
    float* sums  = (float*)alloc(sizeof(float) * 16);
    int* deg     = (int*)alloc(sizeof(int) * NN);
    int* rowptr  = (int*)alloc(sizeof(int) * (NN + 1));
    int* cursor  = (int*)alloc(sizeof(int) * NN);
    int* srt_src = (int*)alloc(sizeof(int) * EE);
    int* srt_eid = (int*)alloc(sizeof(int) * EE);
    int* srt_dst = (int*)alloc(sizeof(int) * EE);
    (void)ws_size; (void)in_sizes; (void)n_in; (void)out_size;

    hipMemsetAsync(sums, 0, 16 * sizeof(float), stream);
    hipMemsetAsync(deg, 0, NN * sizeof(int), stream);

    // bf16 conversions
    k_cvt<<<(NN * 128 / 8 + 255) / 256, 256, 0, stream>>>(x, x_bf, NN * 128);
    k_cvt<<<8, 256, 0, stream>>>(in_w,   inw_b, 16384);
    k_cvt<<<8, 256, 0, stream>>>(lin_w1, w1_b,  16384);
    k_cvt<<<8, 256, 0, stream>>>(lin_w2, w2_b,  16384);
    k_cvt<<<24, 256, 0, stream>>>(jk_w,  jkw_b, 49152);

    k_precompute<<<1, 128, 0, stream>>>(lin_ew1, att_edge1, lin_ew2, att_edge2, enc_w2, enc_b2,
                                        P1, q1, P2, q2);
    k_norms<<<(NN + 3) / 4, 256, 0, stream>>>(x, norms);
    k_encoder<<<(EE + 15) / 16, 256, 0, stream>>>(x_bf, ei, norms, enc_w1, enc_b1,
                                                  P1, q1, P2, q2, ae1, ae2);
    k_redsum<<<128, 256, 0, stream>>>(ae1, ae2, sums);
    k_selfedge<<<1, 64, 0, stream>>>(sums, se1, se2);
    k_hist<<<(EE + 255) / 256, 256, 0, stream>>>(ei, deg);
    k_scan<<<1, 1024, 0, stream>>>(deg, rowptr, cursor);
    k_scatter<<<(EE + 255) / 256, 256, 0, stream>>>(ei, cursor, srt_src, srt_eid, srt_dst);

    int gm = (NN + 127) / 128;
    k_mfma<true ><<<gm, 256, 0, stream>>>(x_bf, inw_b, in_b,    h0b, NN);
    k_mfma<false><<<gm, 256, 0, stream>>>(x_bf, w1_b,  nullptr, xsb, NN);
    k_att<<<(NN + 3) / 4, 256, 0, stream>>>(xsb, att_src1, att_dst1, a_src1, a_dst1);
    k_weights<<<(EE + 255) / 256, 256, 0, stream>>>(srt_src, srt_dst, srt_eid, ae1,
                                                    a_src1, a_dst1, wbuf);
    k_agg<<<NN, 128, 0, stream>>>(rowptr, srt_src, wbuf, a_src1, a_dst1, se1,
                                  xsb, h0b, bias1, g1, bn1, h1b);
    k_mfma<false><<<gm, 256, 0, stream>>>(h1b, w2_b, nullptr, xsb, NN);
    k_att<<<(NN + 3) / 4, 256, 0, stream>>>(xsb, att_src2, att_dst2, a_src2, a_dst2);
    k_weights<<<(EE + 255) / 256, 256, 0, stream>>>(srt_src, srt_dst, srt_eid, ae2,
                                                    a_src2, a_dst2, wbuf);
    k_agg<<<NN, 128, 0, stream>>>(rowptr, srt_src, wbuf, a_src2, a_dst2, se2,
                                  xsb, h1b, bias2, g2, bn2, h2b);
    k_mfma_jk<<<gm, 256, 0, stream>>>(h0b, h1b, h2b, jkw_b, jk_b, out, NN);
}

// Round 5
// 460.126 us; speedup vs baseline: 5.6598x; 1.3135x over previous
//
#include <hip/hip_runtime.h>

#define NN 50000
#define EE 600000
#define FF 128
#define HH 8
#define CC 16
#define DD 128

typedef unsigned short u16;
typedef short bf8 __attribute__((ext_vector_type(8)));
typedef float f4 __attribute__((ext_vector_type(4)));

static __device__ __forceinline__ float b2f(u16 u) {
    union { float f; unsigned i; } v; v.i = (unsigned)u << 16; return v.f;
}
static __device__ __forceinline__ u16 f2b(float f) {
    union { float f; unsigned i; } v; v.f = f;
    unsigned r = v.i + 0x7fff + ((v.i >> 16) & 1);
    return (u16)(r >> 16);
}
// LDS tile swizzle: tile is [128 rows][128 bf16]; 16B-unit index with XOR
static __device__ __forceinline__ int tswz(int row, int u) {
    return (row * 16 + (u ^ (row & 7))) * 8;   // u16 element index
}

// ---------------------------------------------------------------------------
// fp32 -> bf16 bulk convert
// ---------------------------------------------------------------------------
__global__ void k_cvt(const float* __restrict__ src, u16* __restrict__ dst, int n) {
    int i = (blockIdx.x * 256 + threadIdx.x) * 8;
    if (i + 8 <= n) {
        float4 v0 = *(const float4*)(src + i);
        float4 v1 = *(const float4*)(src + i + 4);
        u16 o[8] = {f2b(v0.x), f2b(v0.y), f2b(v0.z), f2b(v0.w),
                    f2b(v1.x), f2b(v1.y), f2b(v1.z), f2b(v1.w)};
        *(uint4*)(dst + i) = *(uint4*)o;
    } else {
        for (int j = i; j < n; ++j) dst[j] = f2b(src[j]);
    }
}

// ---------------------------------------------------------------------------
// K0: fold lin_edge_w + att_edge into M[8][8]; fold encoder layer-2 through M
// ---------------------------------------------------------------------------
__global__ void k_precompute(const float* __restrict__ lew1, const float* __restrict__ ae1,
                             const float* __restrict__ lew2, const float* __restrict__ ae2,
                             const float* __restrict__ enc_w2, const float* __restrict__ enc_b2,
                             float* __restrict__ P1, float* __restrict__ q1,
                             float* __restrict__ P2, float* __restrict__ q2) {
    __shared__ float sM1[64], sM2[64];
    int t = threadIdx.x;  // 128 threads
    {
        int kk = (t & 63) >> 3, h = t & 7;
        const float* lew = (t < 64) ? lew1 : lew2;
        const float* ae  = (t < 64) ? ae1  : ae2;
        float s = 0.f;
        for (int c = 0; c < 16; ++c) s += lew[(h * 16 + c) * 8 + kk] * ae[h * 16 + c];
        if (t < 64) sM1[kk * 8 + h] = s; else sM2[kk * 8 + h] = s;
    }
    __syncthreads();
    int c = t >> 3, h = t & 7;
    float p1 = 0.f, p2 = 0.f;
    for (int k = 0; k < 8; ++k) {
        float w = enc_w2[k * 16 + c];
        p1 += w * sM1[k * 8 + h];
        p2 += w * sM2[k * 8 + h];
    }
    P1[c * 8 + h] = p1;
    P2[c * 8 + h] = p2;
    if (t < 8) {
        float s1 = 0.f, s2 = 0.f;
        for (int k = 0; k < 8; ++k) { float b = enc_b2[k]; s1 += b * sM1[k * 8 + t]; s2 += b * sM2[k * 8 + t]; }
        q1[t] = s1; q2[t] = s2;
    }
}

// ---------------------------------------------------------------------------
// K1: node squared norms (fp32 x for accuracy)
// ---------------------------------------------------------------------------
__global__ void k_norms(const float* __restrict__ x, float* __restrict__ norms) {
    int wid = threadIdx.x >> 6, lane = threadIdx.x & 63;
    int row = blockIdx.x * 4 + wid;
    if (row >= NN) return;
    const float* xr = x + (size_t)row * FF;
    float a = xr[lane], b = xr[lane + 64];
    float s = a * a + b * b;
    for (int off = 1; off < 64; off <<= 1) s += __shfl_xor(s, off, 64);
    if (lane == 0) norms[row] = s;
}

// ---------------------------------------------------------------------------
// K2: edge encoder, CSR (dst-sorted) order: consecutive edges share dst row
// -> L1/L2 hits on the dst gather. 16 lanes per edge. Outputs CSR-ordered ae.
// ---------------------------------------------------------------------------
__global__ void k_encoder(const u16* __restrict__ xb,
                          const int* __restrict__ srt_src, const int* __restrict__ srt_dst,
                          const float* __restrict__ norms,
                          const float* __restrict__ enc_w1, const float* __restrict__ enc_b1,
                          const float* __restrict__ P1, const float* __restrict__ q1,
                          const float* __restrict__ P2, const float* __restrict__ q2,
                          float* __restrict__ ae1out, float* __restrict__ ae2out) {
    __shared__ float sA[16], sB[16], sC[16], sb[16];
    __shared__ float sP[256], sq[16];
    __shared__ float hidbuf[16][17];
    int t = threadIdx.x;
    if (t < 16) {
        float w0 = enc_w1[t * 4 + 0], w1 = enc_w1[t * 4 + 1];
        float w2 = enc_w1[t * 4 + 2], w3 = enc_w1[t * 4 + 3];
        sA[t] = w0 - 2.f * w1;
        sB[t] = w1 + w2;
        sC[t] = w1 + w3;
        sb[t] = enc_b1[t];
    }
    if (t < 128) sP[t] = P1[t]; else if (t < 256) sP[t] = P2[t - 128];
    if (t >= 16 && t < 24) sq[t - 16] = q1[t - 16];
    if (t >= 24 && t < 32) sq[t - 16] = q2[t - 24];
    __syncthreads();
    int eq = t >> 4, l = t & 15;
    int e = blockIdx.x * 16 + eq;
    if (e >= EE) return;
    int s_ = srt_src[e], d_ = srt_dst[e];
    uint4 av = *(const uint4*)(xb + (size_t)s_ * FF + l * 8);
    uint4 bv = *(const uint4*)(xb + (size_t)d_ * FF + l * 8);
    float af[8], bf[8];
    af[0] = b2f((u16)(av.x & 0xffff)); af[1] = b2f((u16)(av.x >> 16));
    af[2] = b2f((u16)(av.y & 0xffff)); af[3] = b2f((u16)(av.y >> 16));
    af[4] = b2f((u16)(av.z & 0xffff)); af[5] = b2f((u16)(av.z >> 16));
    af[6] = b2f((u16)(av.w & 0xffff)); af[7] = b2f((u16)(av.w >> 16));
    bf[0] = b2f((u16)(bv.x & 0xffff)); bf[1] = b2f((u16)(bv.x >> 16));
    bf[2] = b2f((u16)(bv.y & 0xffff)); bf[3] = b2f((u16)(bv.y >> 16));
    bf[4] = b2f((u16)(bv.z & 0xffff)); bf[5] = b2f((u16)(bv.z >> 16));
    bf[6] = b2f((u16)(bv.w & 0xffff)); bf[7] = b2f((u16)(bv.w >> 16));
    float dot = 0.f;
    #pragma unroll
    for (int j = 0; j < 8; ++j) dot += af[j] * bf[j];
    #pragma unroll
    for (int off = 1; off < 16; off <<= 1) dot += __shfl_xor(dot, off, 64);
    float ni = norms[s_], nj = norms[d_];
    float v = sA[l] * dot + sB[l] * ni + sC[l] * nj + sb[l];
    hidbuf[eq][l] = v > 0.f ? v : 0.f;
    int conv = l >> 3, h = l & 7;
    const float* P = sP + conv * 128;
    float a = sq[conv * 8 + h];
    #pragma unroll
    for (int c = 0; c < 16; ++c) a += hidbuf[eq][c] * P[c * 8 + h];
    if (conv == 0) ae1out[(size_t)e * 8 + h] = a;
    else           ae2out[(size_t)e * 8 + h] = a;
}

// ---------------------------------------------------------------------------
// K2b: grid-stride reduction of ae1/ae2 per head -> sums[16]
// ---------------------------------------------------------------------------
__global__ void k_redsum(const float* __restrict__ a1, const float* __restrict__ a2,
                         float* __restrict__ sums) {
    int tid = threadIdx.x;  // 256
    int gid = blockIdx.x * 256 + tid;
    int stride = gridDim.x * 256;
    float s1 = 0.f, s2 = 0.f;
    for (int i = gid; i < EE * 8; i += stride) { s1 += a1[i]; s2 += a2[i]; }
    for (int off = 8; off < 64; off <<= 1) { s1 += __shfl_xor(s1, off, 64); s2 += __shfl_xor(s2, off, 64); }
    __shared__ float b1[4][8], b2[4][8];
    int wid = tid >> 6, lane = tid & 63;
    if (lane < 8) { b1[wid][lane] = s1; b2[wid][lane] = s2; }
    __syncthreads();
    if (tid < 8) {
        float t1 = b1[0][tid] + b1[1][tid] + b1[2][tid] + b1[3][tid];
        float t2 = b2[0][tid] + b2[1][tid] + b2[2][tid] + b2[3][tid];
        atomicAdd(&sums[tid], t1);
        atomicAdd(&sums[8 + tid], t2);
    }
}

__global__ void k_selfedge(const float* __restrict__ sums, float* __restrict__ se1, float* __restrict__ se2) {
    int t = threadIdx.x;
    if (t < 8) se1[t] = sums[t] * (1.f / (float)EE);
    else if (t < 16) se2[t - 8] = sums[t] * (1.f / (float)EE);
}

// ---------------------------------------------------------------------------
// CSR build by dst
// ---------------------------------------------------------------------------
__global__ void k_hist(const int* __restrict__ ei, int* __restrict__ deg) {
    int e = blockIdx.x * 256 + threadIdx.x;
    if (e < EE) atomicAdd(&deg[ei[EE + e]], 1);
}

__global__ void k_scan(const int* __restrict__ deg, int* __restrict__ rowptr, int* __restrict__ cursor) {
    __shared__ int wsum[16];
    __shared__ int carry;
    int t = threadIdx.x, wid = t >> 6, lane = t & 63;
    if (t == 0) carry = 0;
    __syncthreads();
    for (int base = 0; base < NN; base += 1024) {
        int v = (base + t < NN) ? deg[base + t] : 0;
        int sc = v;
        #pragma unroll
        for (int off = 1; off < 64; off <<= 1) { int n = __shfl_up(sc, off, 64); if (lane >= off) sc += n; }
        if (lane == 63) wsum[wid] = sc;
        __syncthreads();
        if (t < 16) {
            int ws = wsum[t];
            #pragma unroll
            for (int off = 1; off < 16; off <<= 1) { int n = __shfl_up(ws, off, 64); if (t >= off) ws += n; }
            wsum[t] = ws;
        }
        __syncthreads();
        int ex = carry + (wid ? wsum[wid - 1] : 0) + sc - v;
        if (base + t < NN) { rowptr[base + t] = ex; cursor[base + t] = ex; }
        __syncthreads();
        if (t == 0) carry += wsum[15];
        __syncthreads();
    }
    if (t == 0) rowptr[NN] = carry;
}

__global__ void k_scatter(const int* __restrict__ ei, int* __restrict__ cursor,
                          int* __restrict__ srt_src, int* __restrict__ srt_dst) {
    int e = blockIdx.x * 256 + threadIdx.x;
    if (e < EE) {
        int d = ei[EE + e];
        int pos = atomicAdd(&cursor[d], 1);
        srt_src[pos] = ei[e];
        srt_dst[pos] = d;
    }
}

// ---------------------------------------------------------------------------
// bf16 MFMA GEMM: out_bf16[N,128] = X_bf[N,128] @ W_bf^T (+bias)
// ---------------------------------------------------------------------------
template <bool BIAS>
__global__ __launch_bounds__(256, 2) void k_mfma(const u16* __restrict__ X,
                                                 const u16* __restrict__ W,
                                                 const float* __restrict__ bias,
                                                 u16* __restrict__ out, int nrows) {
    __shared__ __align__(16) u16 tA[128 * 128];
    __shared__ __align__(16) u16 tB[128 * 128];
    int t = threadIdx.x;
    int r0 = blockIdx.x * 128;
    #pragma unroll
    for (int it = 0; it < 8; ++it) {
        int idx = it * 256 + t;
        int r = idx >> 4, u = idx & 15;
        uint4 v = make_uint4(0u, 0u, 0u, 0u);
        if (r0 + r < nrows) v = *(const uint4*)(X + (size_t)(r0 + r) * 128 + u * 8);
        *(uint4*)&tA[tswz(r, u)] = v;
        uint4 wv = *(const uint4*)(W + (size_t)r * 128 + u * 8);
        *(uint4*)&tB[tswz(r, u)] = wv;
    }
    __syncthreads();
    int l = t & 63, w = t >> 6;
    int lr = l & 15, lk = l >> 4;
    f4 acc[2][8];
    #pragma unroll
    for (int m = 0; m < 2; ++m)
        #pragma unroll
        for (int n = 0; n < 8; ++n) acc[m][n] = (f4){0.f, 0.f, 0.f, 0.f};
    #pragma unroll
    for (int s = 0; s < 4; ++s) {
        int u = s * 4 + lk;
        bf8 a0 = *(bf8*)&tA[tswz(w * 32 + lr, u)];
        bf8 a1 = *(bf8*)&tA[tswz(w * 32 + 16 + lr, u)];
        #pragma unroll
        for (int n = 0; n < 8; ++n) {
            bf8 b = *(bf8*)&tB[tswz(n * 16 + lr, u)];
            acc[0][n] = __builtin_amdgcn_mfma_f32_16x16x32_bf16(a0, b, acc[0][n], 0, 0, 0);
            acc[1][n] = __builtin_amdgcn_mfma_f32_16x16x32_bf16(a1, b, acc[1][n], 0, 0, 0);
        }
    }
    #pragma unroll
    for (int n = 0; n < 8; ++n) {
        int col = n * 16 + lr;
        float bv = BIAS ? bias[col] : 0.f;
        #pragma unroll
        for (int m = 0; m < 2; ++m) {
            #pragma unroll
            for (int g = 0; g < 4; ++g) {
                int row = r0 + w * 32 + m * 16 + lk * 4 + g;
                if (row < nrows) out[(size_t)row * 128 + col] = f2b(acc[m][n][g] + bv);
            }
        }
    }
}

// ---------------------------------------------------------------------------
// fused JK MFMA GEMM: out_f32 = [h0 h1 h2]_bf @ jk_w_bf^T + jk_b (K=384)
// ---------------------------------------------------------------------------
__global__ __launch_bounds__(256, 2) void k_mfma_jk(const u16* __restrict__ h0,
                                                    const u16* __restrict__ h1,
                                                    const u16* __restrict__ h2,
                                                    const u16* __restrict__ W,
                                                    const float* __restrict__ bias,
                                                    float* __restrict__ out, int nrows) {
    __shared__ __align__(16) u16 tA[128 * 128];
    __shared__ __align__(16) u16 tB[128 * 128];
    int t = threadIdx.x;
    int r0 = blockIdx.x * 128;
    int l = t & 63, w = t >> 6;
    int lr = l & 15, lk = l >> 4;
    f4 acc[2][8];
    #pragma unroll
    for (int m = 0; m < 2; ++m)
        #pragma unroll
        for (int n = 0; n < 8; ++n) acc[m][n] = (f4){0.f, 0.f, 0.f, 0.f};
    for (int seg = 0; seg < 3; ++seg) {
        if (seg) __syncthreads();
        const u16* X = seg == 0 ? h0 : (seg == 1 ? h1 : h2);
        #pragma unroll
        for (int it = 0; it < 8; ++it) {
            int idx = it * 256 + t;
            int r = idx >> 4, u = idx & 15;
            uint4 v = make_uint4(0u, 0u, 0u, 0u);
            if (r0 + r < nrows) v = *(const uint4*)(X + (size_t)(r0 + r) * 128 + u * 8);
            *(uint4*)&tA[tswz(r, u)] = v;
            uint4 wv = *(const uint4*)(W + (size_t)r * 384 + seg * 128 + u * 8);
            *(uint4*)&tB[tswz(r, u)] = wv;
        }
        __syncthreads();
        #pragma unroll
        for (int s = 0; s < 4; ++s) {
            int u = s * 4 + lk;
            bf8 a0 = *(bf8*)&tA[tswz(w * 32 + lr, u)];
            bf8 a1 = *(bf8*)&tA[tswz(w * 32 + 16 + lr, u)];
            #pragma unroll
            for (int n = 0; n < 8; ++n) {
                bf8 b = *(bf8*)&tB[tswz(n * 16 + lr, u)];
                acc[0][n] = __builtin_amdgcn_mfma_f32_16x16x32_bf16(a0, b, acc[0][n], 0, 0, 0);
                acc[1][n] = __builtin_amdgcn_mfma_f32_16x16x32_bf16(a1, b, acc[1][n], 0, 0, 0);
            }
        }
    }
    #pragma unroll
    for (int n = 0; n < 8; ++n) {
        int col = n * 16 + lr;
        float bv = bias[col];
        #pragma unroll
        for (int m = 0; m < 2; ++m) {
            #pragma unroll
            for (int g = 0; g < 4; ++g) {
                int row = r0 + w * 32 + m * 16 + lk * 4 + g;
                if (row < nrows) out[(size_t)row * 128 + col] = acc[m][n][g] + bv;
            }
        }
    }
}

// ---------------------------------------------------------------------------
// per-node attention scores a_src/a_dst (wave per row, bf16 xs)
// ---------------------------------------------------------------------------
__global__ void k_att(const u16* __restrict__ xs, const float* __restrict__ att_src,
                      const float* __restrict__ att_dst,
                      float* __restrict__ a_src, float* __restrict__ a_dst) {
    int wid = threadIdx.x >> 6, lane = threadIdx.x & 63;
    int row = blockIdx.x * 4 + wid;
    if (row >= NN) return;
    const u16* xr = xs + (size_t)row * 128;
    float v0 = b2f(xr[lane]), v1 = b2f(xr[lane + 64]);
    float s0 = v0 * att_src[lane], s1 = v1 * att_src[64 + lane];
    float d0 = v0 * att_dst[lane], d1 = v1 * att_dst[64 + lane];
    for (int off = 1; off < 16; off <<= 1) {
        s0 += __shfl_xor(s0, off, 64); s1 += __shfl_xor(s1, off, 64);
        d0 += __shfl_xor(d0, off, 64); d1 += __shfl_xor(d1, off, 64);
    }
    if ((lane & 15) == 0) {
        int h = lane >> 4;
        a_src[row * 8 + h] = s0;     a_src[row * 8 + 4 + h] = s1;
        a_dst[row * 8 + h] = d0;     a_dst[row * 8 + 4 + h] = d1;
    }
}

// ---------------------------------------------------------------------------
// edge-parallel attention weights in CSR order (ae is CSR-ordered now)
// ---------------------------------------------------------------------------
__global__ void k_weights(const int* __restrict__ srt_src, const int* __restrict__ srt_dst,
                          const float* __restrict__ ae, const float* __restrict__ a_src,
                          const float* __restrict__ a_dst, float* __restrict__ w) {
    int pos = blockIdx.x * 256 + threadIdx.x;
    if (pos >= EE) return;
    int s = srt_src[pos], d = srt_dst[pos];
    const float* as = a_src + (size_t)s * 8;
    const float* ad = a_dst + (size_t)d * 8;
    const float* av = ae + (size_t)pos * 8;
    float4 s0 = *(const float4*)as, s1 = *(const float4*)(as + 4);
    float4 d0 = *(const float4*)ad, d1 = *(const float4*)(ad + 4);
    float4 e0 = *(const float4*)av, e1 = *(const float4*)(av + 4);
    float al[8] = {s0.x + d0.x + e0.x, s0.y + d0.y + e0.y, s0.z + d0.z + e0.z, s0.w + d0.w + e0.w,
                   s1.x + d1.x + e1.x, s1.y + d1.y + e1.y, s1.z + d1.z + e1.z, s1.w + d1.w + e1.w};
    float o[8];
    #pragma unroll
    for (int h = 0; h < 8; ++h) {
        float a = al[h];
        a = a > 0.f ? a : 0.2f * a;
        o[h] = __expf(a);
    }
    float* wp = w + (size_t)pos * 8;
    *(float4*)wp = make_float4(o[0], o[1], o[2], o[3]);
    *(float4*)(wp + 4) = make_float4(o[4], o[5], o[6], o[7]);
}

// ---------------------------------------------------------------------------
// aggregation + bias + ELU + residual + LayerNorm
// one WAVE per node (4 nodes / 256-block), 2 features per lane,
// chunked 8-edge double-buffered pipeline (static reg indices).
// ---------------------------------------------------------------------------
#define LOADC(S, X, W_, base_) { \
    _Pragma("unroll") \
    for (int k = 0; k < 4; ++k) { int ee = (base_) + k; if (ee < en) S[k] = srt_src[ee]; } \
    _Pragma("unroll") \
    for (int k = 0; k < 4; ++k) { int ee = (base_) + k; if (ee < en) { \
        W_[k] = wq[(size_t)ee * 8 + h]; \
        X[k] = *(const unsigned*)(xs + (size_t)S[k] * 128 + lane * 2); } } }

#define COMPC(X, W_, base_) { \
    _Pragma("unroll") \
    for (int k = 0; k < 4; ++k) { int ee = (base_) + k; if (ee < en) { \
        float wc = W_[k]; unsigned xv = X[k]; \
        acc0 += wc * b2f((u16)(xv & 0xffff)); \
        acc1 += wc * b2f((u16)(xv >> 16)); \
        denom += wc; } } }

__global__ __launch_bounds__(256) void k_agg(const int* __restrict__ rowptr,
                      const int* __restrict__ srt_src,
                      const float* __restrict__ wq,
                      const float* __restrict__ a_src, const float* __restrict__ a_dst,
                      const float* __restrict__ se,
                      const u16* __restrict__ xs, const u16* __restrict__ res,
                      const float* __restrict__ bias, const float* __restrict__ gamma,
                      const float* __restrict__ beta, u16* __restrict__ outh) {
    int wv_ = threadIdx.x >> 6, lane = threadIdx.x & 63;
    int i = blockIdx.x * 4 + wv_;
    if (i >= NN) return;
    int h = lane >> 3;                       // head of features 2*lane, 2*lane+1
    int b = rowptr[i], en = rowptr[i + 1];
    float acc0 = 0.f, acc1 = 0.f, denom = 0.f;
    int sa[4], sb[4]; unsigned xa[4], xb[4]; float wa[4], wb[4];
    LOADC(sa, xa, wa, b)
    LOADC(sb, xb, wb, b + 4)
    for (int base = b; base < en; base += 8) {
        COMPC(xa, wa, base)
        LOADC(sa, xa, wa, base + 8)
        COMPC(xb, wb, base + 4)
        LOADC(sb, xb, wb, base + 12)
    }
    {   // self loop (mean edge-attr folded to se[h])
        float al = a_src[i * 8 + h] + a_dst[i * 8 + h] + se[h];
        al = al > 0.f ? al : 0.2f * al;
        float wc = __expf(al);
        unsigned xv = *(const unsigned*)(xs + (size_t)i * 128 + lane * 2);
        denom += wc;
        acc0 += wc * b2f((u16)(xv & 0xffff));
        acc1 += wc * b2f((u16)(xv >> 16));
    }
    float inv = 1.f / (denom + 1e-16f);
    float2 bi = *(const float2*)(bias + lane * 2);
    float v0 = acc0 * inv + bi.x;
    float v1 = acc1 * inv + bi.y;
    v0 = v0 > 0.f ? v0 : (__expf(v0) - 1.f);
    v1 = v1 > 0.f ? v1 : (__expf(v1) - 1.f);
    unsigned rv = *(const unsigned*)(res + (size_t)i * 128 + lane * 2);
    v0 += b2f((u16)(rv & 0xffff));
    v1 += b2f((u16)(rv >> 16));
    float s = v0 + v1, q = v0 * v0 + v1 * v1;
    #pragma unroll
    for (int off = 1; off < 64; off <<= 1) { s += __shfl_xor(s, off, 64); q += __shfl_xor(q, off, 64); }
    float mu = s * (1.f / 128.f);
    float var = q * (1.f / 128.f) - mu * mu;
    float r = rsqrtf(var + 1e-5f);
    float2 ga = *(const float2*)(gamma + lane * 2);
    float2 be = *(const float2*)(beta + lane * 2);
    float o0 = (v0 - mu) * r * ga.x + be.x;
    float o1 = (v1 - mu) * r * ga.y + be.y;
    unsigned ov = (unsigned)f2b(o0) | ((unsigned)f2b(o1) << 16);
    *(unsigned*)(outh + (size_t)i * 128 + lane * 2) = ov;
}

// ---------------------------------------------------------------------------
extern "C" void kernel_launch(void* const* d_in, const int* in_sizes, int n_in,
                              void* d_out, int out_size, void* d_ws, size_t ws_size,
                              hipStream_t stream) {
    const float* x        = (const float*)d_in[0];
    const int*   ei       = (const int*)d_in[1];
    const float* enc_w1   = (const float*)d_in[2];
    const float* enc_b1   = (const float*)d_in[3];
    const float* enc_w2   = (const float*)d_in[4];
    const float* enc_b2   = (const float*)d_in[5];
    const float* in_w     = (const float*)d_in[6];
    const float* in_b     = (const float*)d_in[7];
    const float* lin_w1   = (const float*)d_in[8];
    const float* att_src1 = (const float*)d_in[9];
    const float* att_dst1 = (const float*)d_in[10];
    const float* att_edge1= (const float*)d_in[11];
    const float* lin_ew1  = (const float*)d_in[12];
    const float* bias1    = (const float*)d_in[13];
    const float* lin_w2   = (const float*)d_in[14];
    const float* att_src2 = (const float*)d_in[15];
    const float* att_dst2 = (const float*)d_in[16];
    const float* att_edge2= (const float*)d_in[17];
    const float* lin_ew2  = (const float*)d_in[18];
    const float* bias2    = (const float*)d_in[19];
    const float* g1       = (const float*)d_in[20];
    const float* bn1      = (const float*)d_in[21];
    const float* g2       = (const float*)d_in[22];
    const float* bn2      = (const float*)d_in[23];
    const float* jk_w     = (const float*)d_in[24];
    const float* jk_b     = (const float*)d_in[25];
    float* out = (float*)d_out;

    char* wsp = (char*)d_ws;
    size_t off = 0;
    auto alloc = [&](size_t bytes) -> char* {
        char* p = wsp + off;
        off += (bytes + 255) & ~(size_t)255;
        return p;
    };
    u16* x_bf   = (u16*)alloc(sizeof(u16) * (size_t)NN * 128);
    u16* h0b    = (u16*)alloc(sizeof(u16) * (size_t)NN * 128);
    u16* h1b    = (u16*)alloc(sizeof(u16) * (size_t)NN * 128);
    u16* h2b    = (u16*)alloc(sizeof(u16) * (size_t)NN * 128);
    u16* xsb    = (u16*)alloc(sizeof(u16) * (size_t)NN * 128);
    u16* inw_b  = (u16*)alloc(sizeof(u16) * 16384);
    u16* w1_b   = (u16*)alloc(sizeof(u16) * 16384);
    u16* w2_b   = (u16*)alloc(sizeof(u16) * 16384);
    u16* jkw_b  = (u16*)alloc(sizeof(u16) * 49152);
    float* ae1   = (float*)alloc(sizeof(float) * (size_t)EE * 8);
    float* ae2   = (float*)alloc(sizeof(float) * (size_t)EE * 8);
    float* wbuf  = (float*)alloc(sizeof(float) * (size_t)EE * 8);
    float* norms = (float*)alloc(sizeof(float) * NN);
    float* a_src1= (float*)alloc(sizeof(float) * NN * 8);
    float* a_dst1= (float*)alloc(sizeof(float) * NN * 8);
    float* a_src2= (float*)alloc(sizeof(float) * NN * 8);
    float* a_dst2= (float*)alloc(sizeof(float) * NN * 8);
    float* P1    = (float*)alloc(sizeof(float) * 128);
    float* q1    = (float*)alloc(sizeof(float) * 8);
    float* P2    = (float*)alloc(sizeof(float) * 128);
    float* q2    = (float*)alloc(sizeof(float) * 8);
    float* se1   = (float*)alloc(sizeof(float) * 8);
    float* se2   = (float*)alloc(sizeof(float) * 8);
    float* sums  = (float*)alloc(sizeof(float) * 16);
    int* deg     = (int*)alloc(sizeof(int) * NN);
    int* rowptr  = (int*)alloc(sizeof(int) * (NN + 1));
    int* cursor  = (int*)alloc(sizeof(int) * NN);
    int* srt_src = (int*)alloc(sizeof(int) * EE);
    int* srt_dst = (int*)alloc(sizeof(int) * EE);
    (void)ws_size; (void)in_sizes; (void)n_in; (void)out_size;

    hipMemsetAsync(sums, 0, 16 * sizeof(float), stream);
    hipMemsetAsync(deg, 0, NN * sizeof(int), stream);

    // bf16 conversions
    k_cvt<<<(NN * 128 / 8 + 255) / 256, 256, 0, stream>>>(x, x_bf, NN * 128);
    k_cvt<<<8, 256, 0, stream>>>(in_w,   inw_b, 16384);
    k_cvt<<<8, 256, 0, stream>>>(lin_w1, w1_b,  16384);
    k_cvt<<<8, 256, 0, stream>>>(lin_w2, w2_b,  16384);
    k_cvt<<<24, 256, 0, stream>>>(jk_w,  jkw_b, 49152);

    k_precompute<<<1, 128, 0, stream>>>(lin_ew1, att_edge1, lin_ew2, att_edge2, enc_w2, enc_b2,
                                        P1, q1, P2, q2);
    k_norms<<<(NN + 3) / 4, 256, 0, stream>>>(x, norms);
    // CSR build BEFORE encoder: encoder runs in dst-sorted order
    k_hist<<<(EE + 255) / 256, 256, 0, stream>>>(ei, deg);
    k_scan<<<1, 1024, 0, stream>>>(deg, rowptr, cursor);
    k_scatter<<<(EE + 255) / 256, 256, 0, stream>>>(ei, cursor, srt_src, srt_dst);
    k_encoder<<<(EE + 15) / 16, 256, 0, stream>>>(x_bf, srt_src, srt_dst, norms, enc_w1, enc_b1,
                                                  P1, q1, P2, q2, ae1, ae2);
    k_redsum<<<128, 256, 0, stream>>>(ae1, ae2, sums);
    k_selfedge<<<1, 64, 0, stream>>>(sums, se1, se2);

    int gm = (NN + 127) / 128;
    k_mfma<true ><<<gm, 256, 0, stream>>>(x_bf, inw_b, in_b,    h0b, NN);
    k_mfma<false><<<gm, 256, 0, stream>>>(x_bf, w1_b,  nullptr, xsb, NN);
    k_att<<<(NN + 3) / 4, 256, 0, stream>>>(xsb, att_src1, att_dst1, a_src1, a_dst1);
    k_weights<<<(EE + 255) / 256, 256, 0, stream>>>(srt_src, srt_dst, ae1,
                                                    a_src1, a_dst1, wbuf);
    k_agg<<<(NN + 3) / 4, 256, 0, stream>>>(rowptr, srt_src, wbuf, a_src1, a_dst1, se1,
                                            xsb, h0b, bias1, g1, bn1, h1b);
    k_mfma<false><<<gm, 256, 0, stream>>>(h1b, w2_b, nullptr, xsb, NN);
    k_att<<<(NN + 3) / 4, 256, 0, stream>>>(xsb, att_src2, att_dst2, a_src2, a_dst2);
    k_weights<<<(EE + 255) / 256, 256, 0, stream>>>(srt_src, srt_dst, ae2,
                                                    a_src2, a_dst2, wbuf);
    k_agg<<<(NN + 3) / 4, 256, 0, stream>>>(rowptr, srt_src, wbuf, a_src2, a_dst2, se2,
                                            xsb, h1b, bias2, g2, bn2, h2b);
    k_mfma_jk<<<gm, 256, 0, stream>>>(h0b, h1b, h2b, jkw_b, jk_b, out, NN);
}

// Round 6
// 452.588 us; speedup vs baseline: 5.7541x; 1.0167x over previous
//
#include <hip/hip_runtime.h>

#define NN 50000
#define EE 600000
#define FF 128
#define HH 8
#define CC 16
#define DD 128

typedef unsigned short u16;
typedef short bf8 __attribute__((ext_vector_type(8)));
typedef float f4 __attribute__((ext_vector_type(4)));

static __device__ __forceinline__ float b2f(u16 u) {
    union { float f; unsigned i; } v; v.i = (unsigned)u << 16; return v.f;
}
static __device__ __forceinline__ u16 f2b(float f) {
    union { float f; unsigned i; } v; v.f = f;
    unsigned r = v.i + 0x7fff + ((v.i >> 16) & 1);
    return (u16)(r >> 16);
}
// LDS tile swizzle: tile is [128 rows][128 bf16]; 16B-unit index with XOR
static __device__ __forceinline__ int tswz(int row, int u) {
    return (row * 16 + (u ^ (row & 7))) * 8;   // u16 element index
}

// ---------------------------------------------------------------------------
// weight bf16 conversions, one launch (blocks: 8 in_w, 8 lin_w1, 8 lin_w2, 24 jk)
// ---------------------------------------------------------------------------
__global__ void k_cvtw(const float* __restrict__ s0, u16* __restrict__ d0,
                       const float* __restrict__ s1, u16* __restrict__ d1,
                       const float* __restrict__ s2, u16* __restrict__ d2,
                       const float* __restrict__ s3, u16* __restrict__ d3) {
    int b = blockIdx.x;
    const float* s; u16* d; int base;
    if (b < 8)       { s = s0; d = d0; base = b * 2048; }
    else if (b < 16) { s = s1; d = d1; base = (b - 8) * 2048; }
    else if (b < 24) { s = s2; d = d2; base = (b - 16) * 2048; }
    else             { s = s3; d = d3; base = (b - 24) * 2048; }
    int i = base + threadIdx.x * 8;
    float4 v0 = *(const float4*)(s + i);
    float4 v1 = *(const float4*)(s + i + 4);
    u16 o[8] = {f2b(v0.x), f2b(v0.y), f2b(v0.z), f2b(v0.w),
                f2b(v1.x), f2b(v1.y), f2b(v1.z), f2b(v1.w)};
    *(uint4*)(d + i) = *(uint4*)o;
}

// ---------------------------------------------------------------------------
// K1: fused node norms + x -> bf16 (read x once)
// ---------------------------------------------------------------------------
__global__ void k_prep(const float* __restrict__ x, float* __restrict__ norms,
                       u16* __restrict__ xb) {
    int wid = threadIdx.x >> 6, lane = threadIdx.x & 63;
    int row = blockIdx.x * 4 + wid;
    if (row >= NN) return;
    float2 v = ((const float2*)(x + (size_t)row * FF))[lane];
    float s = v.x * v.x + v.y * v.y;
    #pragma unroll
    for (int off = 1; off < 64; off <<= 1) s += __shfl_xor(s, off, 64);
    if (lane == 0) norms[row] = s;
    unsigned pk = (unsigned)f2b(v.x) | ((unsigned)f2b(v.y) << 16);
    *(unsigned*)(xb + (size_t)row * FF + lane * 2) = pk;
}

// ---------------------------------------------------------------------------
// K0: fold lin_edge_w + att_edge into M[8][8]; fold encoder layer-2 through M
// ---------------------------------------------------------------------------
__global__ void k_precompute(const float* __restrict__ lew1, const float* __restrict__ ae1,
                             const float* __restrict__ lew2, const float* __restrict__ ae2,
                             const float* __restrict__ enc_w2, const float* __restrict__ enc_b2,
                             float* __restrict__ P1, float* __restrict__ q1,
                             float* __restrict__ P2, float* __restrict__ q2) {
    __shared__ float sM1[64], sM2[64];
    int t = threadIdx.x;  // 128 threads
    {
        int kk = (t & 63) >> 3, h = t & 7;
        const float* lew = (t < 64) ? lew1 : lew2;
        const float* ae  = (t < 64) ? ae1  : ae2;
        float s = 0.f;
        for (int c = 0; c < 16; ++c) s += lew[(h * 16 + c) * 8 + kk] * ae[h * 16 + c];
        if (t < 64) sM1[kk * 8 + h] = s; else sM2[kk * 8 + h] = s;
    }
    __syncthreads();
    int c = t >> 3, h = t & 7;
    float p1 = 0.f, p2 = 0.f;
    for (int k = 0; k < 8; ++k) {
        float w = enc_w2[k * 16 + c];
        p1 += w * sM1[k * 8 + h];
        p2 += w * sM2[k * 8 + h];
    }
    P1[c * 8 + h] = p1;
    P2[c * 8 + h] = p2;
    if (t < 8) {
        float s1 = 0.f, s2 = 0.f;
        for (int k = 0; k < 8; ++k) { float b = enc_b2[k]; s1 += b * sM1[k * 8 + t]; s2 += b * sM2[k * 8 + t]; }
        q1[t] = s1; q2[t] = s2;
    }
}

// ---------------------------------------------------------------------------
// K2: edge encoder, CSR order, 16 lanes/edge, bpermute hid exchange (no LDS rt)
// ---------------------------------------------------------------------------
__global__ void k_encoder(const u16* __restrict__ xb,
                          const int* __restrict__ srt_src, const int* __restrict__ srt_dst,
                          const float* __restrict__ norms,
                          const float* __restrict__ enc_w1, const float* __restrict__ enc_b1,
                          const float* __restrict__ P1, const float* __restrict__ q1,
                          const float* __restrict__ P2, const float* __restrict__ q2,
                          float* __restrict__ ae1out, float* __restrict__ ae2out) {
    __shared__ float sA[16], sB[16], sC[16], sb[16];
    __shared__ float sP[256], sq[16];
    int t = threadIdx.x;
    if (t < 16) {
        float w0 = enc_w1[t * 4 + 0], w1 = enc_w1[t * 4 + 1];
        float w2 = enc_w1[t * 4 + 2], w3 = enc_w1[t * 4 + 3];
        sA[t] = w0 - 2.f * w1;
        sB[t] = w1 + w2;
        sC[t] = w1 + w3;
        sb[t] = enc_b1[t];
    }
    if (t < 128) sP[t] = P1[t]; else if (t < 256) sP[t] = P2[t - 128];
    if (t >= 16 && t < 24) sq[t - 16] = q1[t - 16];
    if (t >= 24 && t < 32) sq[t - 16] = q2[t - 24];
    __syncthreads();
    int eq = t >> 4, l = t & 15;
    int e = blockIdx.x * 16 + eq;   // EE % 16 == 0: no partial blocks
    int s_ = srt_src[e], d_ = srt_dst[e];
    uint4 av = *(const uint4*)(xb + (size_t)s_ * FF + l * 8);
    uint4 bv = *(const uint4*)(xb + (size_t)d_ * FF + l * 8);
    float af[8], bf[8];
    af[0] = b2f((u16)(av.x & 0xffff)); af[1] = b2f((u16)(av.x >> 16));
    af[2] = b2f((u16)(av.y & 0xffff)); af[3] = b2f((u16)(av.y >> 16));
    af[4] = b2f((u16)(av.z & 0xffff)); af[5] = b2f((u16)(av.z >> 16));
    af[6] = b2f((u16)(av.w & 0xffff)); af[7] = b2f((u16)(av.w >> 16));
    bf[0] = b2f((u16)(bv.x & 0xffff)); bf[1] = b2f((u16)(bv.x >> 16));
    bf[2] = b2f((u16)(bv.y & 0xffff)); bf[3] = b2f((u16)(bv.y >> 16));
    bf[4] = b2f((u16)(bv.z & 0xffff)); bf[5] = b2f((u16)(bv.z >> 16));
    bf[6] = b2f((u16)(bv.w & 0xffff)); bf[7] = b2f((u16)(bv.w >> 16));
    float dot = 0.f;
    #pragma unroll
    for (int j = 0; j < 8; ++j) dot += af[j] * bf[j];
    #pragma unroll
    for (int off = 1; off < 16; off <<= 1) dot += __shfl_xor(dot, off, 64);
    float ni = norms[s_], nj = norms[d_];
    float v = sA[l] * dot + sB[l] * ni + sC[l] * nj + sb[l];
    float hidv = v > 0.f ? v : 0.f;
    int lbase = (t & 63) & ~15;           // first lane of this edge's 16-group
    int conv = l >> 3, h = l & 7;
    const float* P = sP + conv * 128;
    float a = sq[conv * 8 + h];
    #pragma unroll
    for (int c = 0; c < 16; ++c) {
        float hc = __shfl(hidv, lbase + c, 64);
        a += hc * P[c * 8 + h];
    }
    if (conv == 0) ae1out[(size_t)e * 8 + h] = a;
    else           ae2out[(size_t)e * 8 + h] = a;
}

// ---------------------------------------------------------------------------
// K2b: grid-stride reduction of ae1/ae2 per head -> sums[16]
// ---------------------------------------------------------------------------
__global__ void k_redsum(const float* __restrict__ a1, const float* __restrict__ a2,
                         float* __restrict__ sums) {
    int tid = threadIdx.x;  // 256
    int gid = blockIdx.x * 256 + tid;
    int stride = gridDim.x * 256;
    float s1 = 0.f, s2 = 0.f;
    for (int i = gid; i < EE * 8; i += stride) { s1 += a1[i]; s2 += a2[i]; }
    for (int off = 8; off < 64; off <<= 1) { s1 += __shfl_xor(s1, off, 64); s2 += __shfl_xor(s2, off, 64); }
    __shared__ float b1[4][8], b2[4][8];
    int wid = tid >> 6, lane = tid & 63;
    if (lane < 8) { b1[wid][lane] = s1; b2[wid][lane] = s2; }
    __syncthreads();
    if (tid < 8) {
        float t1 = b1[0][tid] + b1[1][tid] + b1[2][tid] + b1[3][tid];
        float t2 = b2[0][tid] + b2[1][tid] + b2[2][tid] + b2[3][tid];
        atomicAdd(&sums[tid], t1);
        atomicAdd(&sums[8 + tid], t2);
    }
}

__global__ void k_selfedge(const float* __restrict__ sums, float* __restrict__ se1, float* __restrict__ se2) {
    int t = threadIdx.x;
    if (t < 8) se1[t] = sums[t] * (1.f / (float)EE);
    else if (t < 16) se2[t - 8] = sums[t] * (1.f / (float)EE);
}

// ---------------------------------------------------------------------------
// CSR build by dst
// ---------------------------------------------------------------------------
__global__ void k_hist(const int* __restrict__ ei, int* __restrict__ deg) {
    int e = blockIdx.x * 256 + threadIdx.x;
    if (e < EE) atomicAdd(&deg[ei[EE + e]], 1);
}

__global__ void k_scan(const int* __restrict__ deg, int* __restrict__ rowptr, int* __restrict__ cursor) {
    __shared__ int wsum[16];
    __shared__ int carry;
    int t = threadIdx.x, wid = t >> 6, lane = t & 63;
    if (t == 0) carry = 0;
    __syncthreads();
    for (int base = 0; base < NN; base += 1024) {
        int v = (base + t < NN) ? deg[base + t] : 0;
        int sc = v;
        #pragma unroll
        for (int off = 1; off < 64; off <<= 1) { int n = __shfl_up(sc, off, 64); if (lane >= off) sc += n; }
        if (lane == 63) wsum[wid] = sc;
        __syncthreads();
        if (t < 16) {
            int ws = wsum[t];
            #pragma unroll
            for (int off = 1; off < 16; off <<= 1) { int n = __shfl_up(ws, off, 64); if (t >= off) ws += n; }
            wsum[t] = ws;
        }
        __syncthreads();
        int ex = carry + (wid ? wsum[wid - 1] : 0) + sc - v;
        if (base + t < NN) { rowptr[base + t] = ex; cursor[base + t] = ex; }
        __syncthreads();
        if (t == 0) carry += wsum[15];
        __syncthreads();
    }
    if (t == 0) rowptr[NN] = carry;
}

__global__ void k_scatter(const int* __restrict__ ei, int* __restrict__ cursor,
                          int* __restrict__ srt_src, int* __restrict__ srt_dst) {
    int e = blockIdx.x * 256 + threadIdx.x;
    if (e < EE) {
        int d = ei[EE + e];
        int pos = atomicAdd(&cursor[d], 1);
        srt_src[pos] = ei[e];
        srt_dst[pos] = d;
    }
}

// ---------------------------------------------------------------------------
// bf16 MFMA GEMM: out_bf16[N,128] = X_bf[N,128] @ W_bf^T (+bias)
// ---------------------------------------------------------------------------
template <bool BIAS>
__global__ __launch_bounds__(256, 2) void k_mfma(const u16* __restrict__ X,
                                                 const u16* __restrict__ W,
                                                 const float* __restrict__ bias,
                                                 u16* __restrict__ out, int nrows) {
    __shared__ __align__(16) u16 tA[128 * 128];
    __shared__ __align__(16) u16 tB[128 * 128];
    int t = threadIdx.x;
    int r0 = blockIdx.x * 128;
    #pragma unroll
    for (int it = 0; it < 8; ++it) {
        int idx = it * 256 + t;
        int r = idx >> 4, u = idx & 15;
        uint4 v = make_uint4(0u, 0u, 0u, 0u);
        if (r0 + r < nrows) v = *(const uint4*)(X + (size_t)(r0 + r) * 128 + u * 8);
        *(uint4*)&tA[tswz(r, u)] = v;
        uint4 wv = *(const uint4*)(W + (size_t)r * 128 + u * 8);
        *(uint4*)&tB[tswz(r, u)] = wv;
    }
    __syncthreads();
    int l = t & 63, w = t >> 6;
    int lr = l & 15, lk = l >> 4;
    f4 acc[2][8];
    #pragma unroll
    for (int m = 0; m < 2; ++m)
        #pragma unroll
        for (int n = 0; n < 8; ++n) acc[m][n] = (f4){0.f, 0.f, 0.f, 0.f};
    #pragma unroll
    for (int s = 0; s < 4; ++s) {
        int u = s * 4 + lk;
        bf8 a0 = *(bf8*)&tA[tswz(w * 32 + lr, u)];
        bf8 a1 = *(bf8*)&tA[tswz(w * 32 + 16 + lr, u)];
        #pragma unroll
        for (int n = 0; n < 8; ++n) {
            bf8 b = *(bf8*)&tB[tswz(n * 16 + lr, u)];
            acc[0][n] = __builtin_amdgcn_mfma_f32_16x16x32_bf16(a0, b, acc[0][n], 0, 0, 0);
            acc[1][n] = __builtin_amdgcn_mfma_f32_16x16x32_bf16(a1, b, acc[1][n], 0, 0, 0);
        }
    }
    #pragma unroll
    for (int n = 0; n < 8; ++n) {
        int col = n * 16 + lr;
        float bv = BIAS ? bias[col] : 0.f;
        #pragma unroll
        for (int m = 0; m < 2; ++m) {
            #pragma unroll
            for (int g = 0; g < 4; ++g) {
                int row = r0 + w * 32 + m * 16 + lk * 4 + g;
                if (row < nrows) out[(size_t)row * 128 + col] = f2b(acc[m][n][g] + bv);
            }
        }
    }
}

// ---------------------------------------------------------------------------
// fused dual GEMM on shared A-tile: out0 = X@W0^T + b0;  out1 = X@W1^T
// ---------------------------------------------------------------------------
__global__ __launch_bounds__(256, 2) void k_mfma_x2(const u16* __restrict__ X,
                                                    const u16* __restrict__ W0,
                                                    const float* __restrict__ b0,
                                                    const u16* __restrict__ W1,
                                                    u16* __restrict__ out0,
                                                    u16* __restrict__ out1, int nrows) {
    __shared__ __align__(16) u16 tA[128 * 128];
    __shared__ __align__(16) u16 tB[128 * 128];
    int t = threadIdx.x;
    int r0 = blockIdx.x * 128;
    #pragma unroll
    for (int it = 0; it < 8; ++it) {
        int idx = it * 256 + t;
        int r = idx >> 4, u = idx & 15;
        uint4 v = make_uint4(0u, 0u, 0u, 0u);
        if (r0 + r < nrows) v = *(const uint4*)(X + (size_t)(r0 + r) * 128 + u * 8);
        *(uint4*)&tA[tswz(r, u)] = v;
        uint4 wv = *(const uint4*)(W0 + (size_t)r * 128 + u * 8);
        *(uint4*)&tB[tswz(r, u)] = wv;
    }
    __syncthreads();
    int l = t & 63, w = t >> 6;
    int lr = l & 15, lk = l >> 4;
    f4 acc[2][8];
    #pragma unroll
    for (int m = 0; m < 2; ++m)
        #pragma unroll
        for (int n = 0; n < 8; ++n) acc[m][n] = (f4){0.f, 0.f, 0.f, 0.f};
    #pragma unroll
    for (int s = 0; s < 4; ++s) {
        int u = s * 4 + lk;
        bf8 a0 = *(bf8*)&tA[tswz(w * 32 + lr, u)];
        bf8 a1 = *(bf8*)&tA[tswz(w * 32 + 16 + lr, u)];
        #pragma unroll
        for (int n = 0; n < 8; ++n) {
            bf8 b = *(bf8*)&tB[tswz(n * 16 + lr, u)];
            acc[0][n] = __builtin_amdgcn_mfma_f32_16x16x32_bf16(a0, b, acc[0][n], 0, 0, 0);
            acc[1][n] = __builtin_amdgcn_mfma_f32_16x16x32_bf16(a1, b, acc[1][n], 0, 0, 0);
        }
    }
    #pragma unroll
    for (int n = 0; n < 8; ++n) {
        int col = n * 16 + lr;
        float bv = b0[col];
        #pragma unroll
        for (int m = 0; m < 2; ++m)
            #pragma unroll
            for (int g = 0; g < 4; ++g) {
                int row = r0 + w * 32 + m * 16 + lk * 4 + g;
                if (row < nrows) out0[(size_t)row * 128 + col] = f2b(acc[m][n][g] + bv);
            }
    }
    __syncthreads();   // all reads of tB done
    #pragma unroll
    for (int it = 0; it < 8; ++it) {
        int idx = it * 256 + t;
        int r = idx >> 4, u = idx & 15;
        uint4 wv = *(const uint4*)(W1 + (size_t)r * 128 + u * 8);
        *(uint4*)&tB[tswz(r, u)] = wv;
    }
    __syncthreads();
    #pragma unroll
    for (int m = 0; m < 2; ++m)
        #pragma unroll
        for (int n = 0; n < 8; ++n) acc[m][n] = (f4){0.f, 0.f, 0.f, 0.f};
    #pragma unroll
    for (int s = 0; s < 4; ++s) {
        int u = s * 4 + lk;
        bf8 a0 = *(bf8*)&tA[tswz(w * 32 + lr, u)];
        bf8 a1 = *(bf8*)&tA[tswz(w * 32 + 16 + lr, u)];
        #pragma unroll
        for (int n = 0; n < 8; ++n) {
            bf8 b = *(bf8*)&tB[tswz(n * 16 + lr, u)];
            acc[0][n] = __builtin_amdgcn_mfma_f32_16x16x32_bf16(a0, b, acc[0][n], 0, 0, 0);
            acc[1][n] = __builtin_amdgcn_mfma_f32_16x16x32_bf16(a1, b, acc[1][n], 0, 0, 0);
        }
    }
    #pragma unroll
    for (int n = 0; n < 8; ++n) {
        int col = n * 16 + lr;
        #pragma unroll
        for (int m = 0; m < 2; ++m)
            #pragma unroll
            for (int g = 0; g < 4; ++g) {
                int row = r0 + w * 32 + m * 16 + lk * 4 + g;
                if (row < nrows) out1[(size_t)row * 128 + col] = f2b(acc[m][n][g]);
            }
    }
}

// ---------------------------------------------------------------------------
// fused JK MFMA GEMM: out_f32 = [h0 h1 h2]_bf @ jk_w_bf^T + jk_b (K=384)
// ---------------------------------------------------------------------------
__global__ __launch_bounds__(256, 2) void k_mfma_jk(const u16* __restrict__ h0,
                                                    const u16* __restrict__ h1,
                                                    const u16* __restrict__ h2,
                                                    const u16* __restrict__ W,
                                                    const float* __restrict__ bias,
                                                    float* __restrict__ out, int nrows) {
    __shared__ __align__(16) u16 tA[128 * 128];
    __shared__ __align__(16) u16 tB[128 * 128];
    int t = threadIdx.x;
    int r0 = blockIdx.x * 128;
    int l = t & 63, w = t >> 6;
    int lr = l & 15, lk = l >> 4;
    f4 acc[2][8];
    #pragma unroll
    for (int m = 0; m < 2; ++m)
        #pragma unroll
        for (int n = 0; n < 8; ++n) acc[m][n] = (f4){0.f, 0.f, 0.f, 0.f};
    for (int seg = 0; seg < 3; ++seg) {
        if (seg) __syncthreads();
        const u16* X = seg == 0 ? h0 : (seg == 1 ? h1 : h2);
        #pragma unroll
        for (int it = 0; it < 8; ++it) {
            int idx = it * 256 + t;
            int r = idx >> 4, u = idx & 15;
            uint4 v = make_uint4(0u, 0u, 0u, 0u);
            if (r0 + r < nrows) v = *(const uint4*)(X + (size_t)(r0 + r) * 128 + u * 8);
            *(uint4*)&tA[tswz(r, u)] = v;
            uint4 wv = *(const uint4*)(W + (size_t)r * 384 + seg * 128 + u * 8);
            *(uint4*)&tB[tswz(r, u)] = wv;
        }
        __syncthreads();
        #pragma unroll
        for (int s = 0; s < 4; ++s) {
            int u = s * 4 + lk;
            bf8 a0 = *(bf8*)&tA[tswz(w * 32 + lr, u)];
            bf8 a1 = *(bf8*)&tA[tswz(w * 32 + 16 + lr, u)];
            #pragma unroll
            for (int n = 0; n < 8; ++n) {
                bf8 b = *(bf8*)&tB[tswz(n * 16 + lr, u)];
                acc[0][n] = __builtin_amdgcn_mfma_f32_16x16x32_bf16(a0, b, acc[0][n], 0, 0, 0);
                acc[1][n] = __builtin_amdgcn_mfma_f32_16x16x32_bf16(a1, b, acc[1][n], 0, 0, 0);
            }
        }
    }
    #pragma unroll
    for (int n = 0; n < 8; ++n) {
        int col = n * 16 + lr;
        float bv = bias[col];
        #pragma unroll
        for (int m = 0; m < 2; ++m) {
            #pragma unroll
            for (int g = 0; g < 4; ++g) {
                int row = r0 + w * 32 + m * 16 + lk * 4 + g;
                if (row < nrows) out[(size_t)row * 128 + col] = acc[m][n][g] + bv;
            }
        }
    }
}

// ---------------------------------------------------------------------------
// per-node attention scores a_src/a_dst (wave per row, bf16 xs)
// ---------------------------------------------------------------------------
__global__ void k_att(const u16* __restrict__ xs, const float* __restrict__ att_src,
                      const float* __restrict__ att_dst,
                      float* __restrict__ a_src, float* __restrict__ a_dst) {
    int wid = threadIdx.x >> 6, lane = threadIdx.x & 63;
    int row = blockIdx.x * 4 + wid;
    if (row >= NN) return;
    const u16* xr = xs + (size_t)row * 128;
    float v0 = b2f(xr[lane]), v1 = b2f(xr[lane + 64]);
    float s0 = v0 * att_src[lane], s1 = v1 * att_src[64 + lane];
    float d0 = v0 * att_dst[lane], d1 = v1 * att_dst[64 + lane];
    for (int off = 1; off < 16; off <<= 1) {
        s0 += __shfl_xor(s0, off, 64); s1 += __shfl_xor(s1, off, 64);
        d0 += __shfl_xor(d0, off, 64); d1 += __shfl_xor(d1, off, 64);
    }
    if ((lane & 15) == 0) {
        int h = lane >> 4;
        a_src[row * 8 + h] = s0;     a_src[row * 8 + 4 + h] = s1;
        a_dst[row * 8 + h] = d0;     a_dst[row * 8 + 4 + h] = d1;
    }
}

// ---------------------------------------------------------------------------
// aggregation with INLINE attention weights + bias + ELU + residual + LayerNorm
// one WAVE per node, 2 features per lane, 8-edge double-buffered pipeline.
// ---------------------------------------------------------------------------
#define LOADC(S, X, AS, AE, base_) { \
    _Pragma("unroll") \
    for (int k = 0; k < 4; ++k) { int ee = (base_) + k; if (ee < en) S[k] = srt_src[ee]; } \
    _Pragma("unroll") \
    for (int k = 0; k < 4; ++k) { int ee = (base_) + k; if (ee < en) { \
        AE[k] = aeq[(size_t)ee * 8 + h]; \
        AS[k] = a_src[(size_t)S[k] * 8 + h]; \
        X[k] = *(const unsigned*)(xs + (size_t)S[k] * 128 + lane * 2); } } }

#define COMPC(X, AS, AE, base_) { \
    _Pragma("unroll") \
    for (int k = 0; k < 4; ++k) { int ee = (base_) + k; if (ee < en) { \
        float al = AS[k] + adst + AE[k]; \
        al = al > 0.f ? al : 0.2f * al; \
        float wc = __expf(al); unsigned xv = X[k]; \
        acc0 += wc * b2f((u16)(xv & 0xffff)); \
        acc1 += wc * b2f((u16)(xv >> 16)); \
        denom += wc; } } }

__global__ __launch_bounds__(256) void k_agg(const int* __restrict__ rowptr,
                      const int* __restrict__ srt_src,
                      const float* __restrict__ aeq,
                      const float* __restrict__ a_src, const float* __restrict__ a_dst,
                      const float* __restrict__ se,
                      const u16* __restrict__ xs, const u16* __restrict__ res,
                      const float* __restrict__ bias, const float* __restrict__ gamma,
                      const float* __restrict__ beta, u16* __restrict__ outh) {
    int wv_ = threadIdx.x >> 6, lane = threadIdx.x & 63;
    int i = blockIdx.x * 4 + wv_;
    if (i >= NN) return;
    int h = lane >> 3;                       // head of features 2*lane, 2*lane+1
    float adst = a_dst[i * 8 + h];
    int b = rowptr[i], en = rowptr[i + 1];
    float acc0 = 0.f, acc1 = 0.f, denom = 0.f;
    int sa[4], sb[4]; unsigned xa[4], xb[4]; float asa[4], asb[4], aea[4], aeb[4];
    LOADC(sa, xa, asa, aea, b)
    LOADC(sb, xb, asb, aeb, b + 4)
    for (int base = b; base < en; base += 8) {
        COMPC(xa, asa, aea, base)
        LOADC(sa, xa, asa, aea, base + 8)
        COMPC(xb, asb, aeb, base + 4)
        LOADC(sb, xb, asb, aeb, base + 12)
    }
    {   // self loop (mean edge-attr folded to se[h])
        float al = a_src[i * 8 + h] + adst + se[h];
        al = al > 0.f ? al : 0.2f * al;
        float wc = __expf(al);
        unsigned xv = *(const unsigned*)(xs + (size_t)i * 128 + lane * 2);
        denom += wc;
        acc0 += wc * b2f((u16)(xv & 0xffff));
        acc1 += wc * b2f((u16)(xv >> 16));
    }
    float inv = 1.f / (denom + 1e-16f);
    float2 bi = *(const float2*)(bias + lane * 2);
    float v0 = acc0 * inv + bi.x;
    float v1 = acc1 * inv + bi.y;
    v0 = v0 > 0.f ? v0 : (__expf(v0) - 1.f);
    v1 = v1 > 0.f ? v1 : (__expf(v1) - 1.f);
    unsigned rv = *(const unsigned*)(res + (size_t)i * 128 + lane * 2);
    v0 += b2f((u16)(rv & 0xffff));
    v1 += b2f((u16)(rv >> 16));
    float s = v0 + v1, q = v0 * v0 + v1 * v1;
    #pragma unroll
    for (int off = 1; off < 64; off <<= 1) { s += __shfl_xor(s, off, 64); q += __shfl_xor(q, off, 64); }
    float mu = s * (1.f / 128.f);
    float var = q * (1.f / 128.f) - mu * mu;
    float r = rsqrtf(var + 1e-5f);
    float2 ga = *(const float2*)(gamma + lane * 2);
    float2 be = *(const float2*)(beta + lane * 2);
    float o0 = (v0 - mu) * r * ga.x + be.x;
    float o1 = (v1 - mu) * r * ga.y + be.y;
    unsigned ov = (unsigned)f2b(o0) | ((unsigned)f2b(o1) << 16);
    *(unsigned*)(outh + (size_t)i * 128 + lane * 2) = ov;
}

// ---------------------------------------------------------------------------
extern "C" void kernel_launch(void* const* d_in, const int* in_sizes, int n_in,
                              void* d_out, int out_size, void* d_ws, size_t ws_size,
                              hipStream_t stream) {
    const float* x        = (const float*)d_in[0];
    const int*   ei       = (const int*)d_in[1];
    const float* enc_w1   = (const float*)d_in[2];
    const float* enc_b1   = (const float*)d_in[3];
    const float* enc_w2   = (const float*)d_in[4];
    const float* enc_b2   = (const float*)d_in[5];
    const float* in_w     = (const float*)d_in[6];
    const float* in_b     = (const float*)d_in[7];
    const float* lin_w1   = (const float*)d_in[8];
    const float* att_src1 = (const float*)d_in[9];
    const float* att_dst1 = (const float*)d_in[10];
    const float* att_edge1= (const float*)d_in[11];
    const float* lin_ew1  = (const float*)d_in[12];
    const float* bias1    = (const float*)d_in[13];
    const float* lin_w2   = (const float*)d_in[14];
    const float* att_src2 = (const float*)d_in[15];
    const float* att_dst2 = (const float*)d_in[16];
    const float* att_edge2= (const float*)d_in[17];
    const float* lin_ew2  = (const float*)d_in[18];
    const float* bias2    = (const float*)d_in[19];
    const float* g1       = (const float*)d_in[20];
    const float* bn1      = (const float*)d_in[21];
    const float* g2       = (const float*)d_in[22];
    const float* bn2      = (const float*)d_in[23];
    const float* jk_w     = (const float*)d_in[24];
    const float* jk_b     = (const float*)d_in[25];
    float* out = (float*)d_out;

    char* wsp = (char*)d_ws;
    size_t off = 0;
    auto alloc = [&](size_t bytes) -> char* {
        char* p = wsp + off;
        off += (bytes + 255) & ~(size_t)255;
        return p;
    };
    u16* x_bf   = (u16*)alloc(sizeof(u16) * (size_t)NN * 128);
    u16* h0b    = (u16*)alloc(sizeof(u16) * (size_t)NN * 128);
    u16* h1b    = (u16*)alloc(sizeof(u16) * (size_t)NN * 128);
    u16* h2b    = (u16*)alloc(sizeof(u16) * (size_t)NN * 128);
    u16* xsb    = (u16*)alloc(sizeof(u16) * (size_t)NN * 128);
    u16* inw_b  = (u16*)alloc(sizeof(u16) * 16384);
    u16* w1_b   = (u16*)alloc(sizeof(u16) * 16384);
    u16* w2_b   = (u16*)alloc(sizeof(u16) * 16384);
    u16* jkw_b  = (u16*)alloc(sizeof(u16) * 49152);
    float* ae1   = (float*)alloc(sizeof(float) * (size_t)EE * 8);
    float* ae2   = (float*)alloc(sizeof(float) * (size_t)EE * 8);
    float* norms = (float*)alloc(sizeof(float) * NN);
    float* a_src1= (float*)alloc(sizeof(float) * NN * 8);
    float* a_dst1= (float*)alloc(sizeof(float) * NN * 8);
    float* a_src2= (float*)alloc(sizeof(float) * NN * 8);
    float* a_dst2= (float*)alloc(sizeof(float) * NN * 8);
    float* P1    = (float*)alloc(sizeof(float) * 128);
    float* q1    = (float*)alloc(sizeof(float) * 8);
    float* P2    = (float*)alloc(sizeof(float) * 128);
    float* q2    = (float*)alloc(sizeof(float) * 8);
    float* se1   = (float*)alloc(sizeof(float) * 8);
    float* se2   = (float*)alloc(sizeof(float) * 8);
    float* sums  = (float*)alloc(sizeof(float) * 16);
    int* deg     = (int*)alloc(sizeof(int) * NN);
    int* rowptr  = (int*)alloc(sizeof(int) * (NN + 1));
    int* cursor  = (int*)alloc(sizeof(int) * NN);
    int* srt_src = (int*)alloc(sizeof(int) * EE);
    int* srt_dst = (int*)alloc(sizeof(int) * EE);
    (void)ws_size; (void)in_sizes; (void)n_in; (void)out_size;

    hipMemsetAsync(sums, 0, 16 * sizeof(float), stream);
    hipMemsetAsync(deg, 0, NN * sizeof(int), stream);

    k_cvtw<<<48, 256, 0, stream>>>(in_w, inw_b, lin_w1, w1_b, lin_w2, w2_b, jk_w, jkw_b);
    k_prep<<<(NN + 3) / 4, 256, 0, stream>>>(x, norms, x_bf);
    k_precompute<<<1, 128, 0, stream>>>(lin_ew1, att_edge1, lin_ew2, att_edge2, enc_w2, enc_b2,
                                        P1, q1, P2, q2);
    k_hist<<<(EE + 255) / 256, 256, 0, stream>>>(ei, deg);
    k_scan<<<1, 1024, 0, stream>>>(deg, rowptr, cursor);
    k_scatter<<<(EE + 255) / 256, 256, 0, stream>>>(ei, cursor, srt_src, srt_dst);
    k_encoder<<<EE / 16, 256, 0, stream>>>(x_bf, srt_src, srt_dst, norms, enc_w1, enc_b1,
                                           P1, q1, P2, q2, ae1, ae2);
    k_redsum<<<128, 256, 0, stream>>>(ae1, ae2, sums);
    k_selfedge<<<1, 64, 0, stream>>>(sums, se1, se2);

    int gm = (NN + 127) / 128;
    k_mfma_x2<<<gm, 256, 0, stream>>>(x_bf, inw_b, in_b, w1_b, h0b, xsb, NN);
    k_att<<<(NN + 3) / 4, 256, 0, stream>>>(xsb, att_src1, att_dst1, a_src1, a_dst1);
    k_agg<<<(NN + 3) / 4, 256, 0, stream>>>(rowptr, srt_src, ae1, a_src1, a_dst1, se1,
                                            xsb, h0b, bias1, g1, bn1, h1b);
    k_mfma<false><<<gm, 256, 0, stream>>>(h1b, w2_b, nullptr, xsb, NN);
    k_att<<<(NN + 3) / 4, 256, 0, stream>>>(xsb, att_src2, att_dst2, a_src2, a_dst2);
    k_agg<<<(NN + 3) / 4, 256, 0, stream>>>(rowptr, srt_src, ae2, a_src2, a_dst2, se2,
                                            xsb, h1b, bias2, g2, bn2, h2b);
    k_mfma_jk<<<gm, 256, 0, stream>>>(h0b, h1b, h2b, jkw_b, jk_b, out, NN);
}

// Round 7
// 411.493 us; speedup vs baseline: 6.3288x; 1.0999x over previous
//
#include <hip/hip_runtime.h>

#define NN 50000
#define EE 600000
#define FF 128
#define HH 8
#define CC 16
#define DD 128

typedef unsigned short u16;
typedef short bf8 __attribute__((ext_vector_type(8)));
typedef float f4 __attribute__((ext_vector_type(4)));

static __device__ __forceinline__ float b2f(u16 u) {
    union { float f; unsigned i; } v; v.i = (unsigned)u << 16; return v.f;
}
static __device__ __forceinline__ float lo2f(unsigned x) {
    union { float f; unsigned i; } v; v.i = x << 16; return v.f;
}
static __device__ __forceinline__ float hi2f(unsigned x) {
    union { float f; unsigned i; } v; v.i = x & 0xffff0000u; return v.f;
}
static __device__ __forceinline__ u16 f2b(float f) {
    union { float f; unsigned i; } v; v.f = f;
    unsigned r = v.i + 0x7fff + ((v.i >> 16) & 1);
    return (u16)(r >> 16);
}
// LDS tile swizzle: tile is [128 rows][128 bf16]; 16B-unit index with XOR
static __device__ __forceinline__ int tswz(int row, int u) {
    return (row * 16 + (u ^ (row & 7))) * 8;   // u16 element index
}

// ---------------------------------------------------------------------------
// MEGA prep kernel: blocks [0,12500) node norms + x->bf16; [12500,12548) weight
// cvt; 12548 precompute (fold lin_edge_w+att_edge, encoder L2 through it);
// [12549, 12549+2344) degree histogram.
// ---------------------------------------------------------------------------
#define NBP 12500
__global__ void k_prep(const float* __restrict__ x, float* __restrict__ norms,
                       u16* __restrict__ xb,
                       const float* __restrict__ s0, u16* __restrict__ d0,
                       const float* __restrict__ s1, u16* __restrict__ d1,
                       const float* __restrict__ s2, u16* __restrict__ d2,
                       const float* __restrict__ s3, u16* __restrict__ d3,
                       const float* __restrict__ lew1, const float* __restrict__ aew1,
                       const float* __restrict__ lew2, const float* __restrict__ aew2,
                       const float* __restrict__ enc_w2, const float* __restrict__ enc_b2,
                       float* __restrict__ P1, float* __restrict__ q1,
                       float* __restrict__ P2, float* __restrict__ q2,
                       const int* __restrict__ ei, int* __restrict__ deg) {
    __shared__ float sM1[64], sM2[64];
    int bb = blockIdx.x;
    int t = threadIdx.x;
    if (bb < NBP) {
        int wid = t >> 6, lane = t & 63;
        int row = bb * 4 + wid;
        float2 v = ((const float2*)(x + (size_t)row * FF))[lane];
        float s = v.x * v.x + v.y * v.y;
        #pragma unroll
        for (int off = 1; off < 64; off <<= 1) s += __shfl_xor(s, off, 64);
        if (lane == 0) norms[row] = s;
        unsigned pk = (unsigned)f2b(v.x) | ((unsigned)f2b(v.y) << 16);
        *(unsigned*)(xb + (size_t)row * FF + lane * 2) = pk;
    } else if (bb < NBP + 48) {
        int b = bb - NBP;
        const float* s; u16* d; int base;
        if (b < 8)       { s = s0; d = d0; base = b * 2048; }
        else if (b < 16) { s = s1; d = d1; base = (b - 8) * 2048; }
        else if (b < 24) { s = s2; d = d2; base = (b - 16) * 2048; }
        else             { s = s3; d = d3; base = (b - 24) * 2048; }
        int i = base + t * 8;
        float4 v0 = *(const float4*)(s + i);
        float4 v1 = *(const float4*)(s + i + 4);
        u16 o[8] = {f2b(v0.x), f2b(v0.y), f2b(v0.z), f2b(v0.w),
                    f2b(v1.x), f2b(v1.y), f2b(v1.z), f2b(v1.w)};
        *(uint4*)(d + i) = *(uint4*)o;
    } else if (bb == NBP + 48) {
        if (t < 128) {
            int kk = (t & 63) >> 3, h = t & 7;
            const float* lew = (t < 64) ? lew1 : lew2;
            const float* ae  = (t < 64) ? aew1 : aew2;
            float s = 0.f;
            for (int c = 0; c < 16; ++c) s += lew[(h * 16 + c) * 8 + kk] * ae[h * 16 + c];
            if (t < 64) sM1[kk * 8 + h] = s; else sM2[kk * 8 + h] = s;
        }
        __syncthreads();
        if (t < 128) {
            int c = t >> 3, h = t & 7;
            float p1 = 0.f, p2 = 0.f;
            for (int k = 0; k < 8; ++k) {
                float w = enc_w2[k * 16 + c];
                p1 += w * sM1[k * 8 + h];
                p2 += w * sM2[k * 8 + h];
            }
            P1[c * 8 + h] = p1;
            P2[c * 8 + h] = p2;
            if (t < 8) {
                float x1 = 0.f, x2 = 0.f;
                for (int k = 0; k < 8; ++k) { float b = enc_b2[k]; x1 += b * sM1[k * 8 + t]; x2 += b * sM2[k * 8 + t]; }
                q1[t] = x1; q2[t] = x2;
            }
        }
    } else {
        int e = (bb - NBP - 49) * 256 + t;
        if (e < EE) atomicAdd(&deg[ei[EE + e]], 1);
    }
}

// ---------------------------------------------------------------------------
// K2: edge encoder, CSR order, 16 lanes/edge, 4 edges per thread-group.
// P preloaded in registers; hid exchanged through wave-local LDS (broadcast).
// ---------------------------------------------------------------------------
__global__ void k_encoder(const u16* __restrict__ xb,
                          const int* __restrict__ srt_src, const int* __restrict__ srt_dst,
                          const float* __restrict__ norms,
                          const float* __restrict__ enc_w1, const float* __restrict__ enc_b1,
                          const float* __restrict__ P1, const float* __restrict__ q1,
                          const float* __restrict__ P2, const float* __restrict__ q2,
                          float* __restrict__ ae1out, float* __restrict__ ae2out) {
    __shared__ float hidbuf[16][17];
    int t = threadIdx.x, eq = t >> 4, l = t & 15;
    int conv = l >> 3, h = l & 7;
    float w0 = enc_w1[l * 4 + 0], w1 = enc_w1[l * 4 + 1];
    float w2 = enc_w1[l * 4 + 2], w3 = enc_w1[l * 4 + 3];
    float cA = w0 - 2.f * w1, cB = w1 + w2, cC = w1 + w3, cb = enc_b1[l];
    const float* Ps = conv ? P2 : P1;
    float Preg[16];
    #pragma unroll
    for (int c = 0; c < 16; ++c) Preg[c] = Ps[c * 8 + h];
    float qreg = conv ? q2[h] : q1[h];
    float* outp = conv ? ae2out : ae1out;
    int e0 = blockIdx.x * 64 + eq;
    #pragma unroll 1
    for (int j = 0; j < 4; ++j) {
        int e = e0 + j * 16;
        int s_ = srt_src[e], d_ = srt_dst[e];
        uint4 av = *(const uint4*)(xb + (size_t)s_ * FF + l * 8);
        uint4 bv = *(const uint4*)(xb + (size_t)d_ * FF + l * 8);
        float dot = lo2f(av.x) * lo2f(bv.x) + hi2f(av.x) * hi2f(bv.x)
                  + lo2f(av.y) * lo2f(bv.y) + hi2f(av.y) * hi2f(bv.y)
                  + lo2f(av.z) * lo2f(bv.z) + hi2f(av.z) * hi2f(bv.z)
                  + lo2f(av.w) * lo2f(bv.w) + hi2f(av.w) * hi2f(bv.w);
        #pragma unroll
        for (int off = 1; off < 16; off <<= 1) dot += __shfl_xor(dot, off, 64);
        float ni = norms[s_], nj = norms[d_];
        float v = cA * dot + cB * ni + cC * nj + cb;
        hidbuf[eq][l] = v > 0.f ? v : 0.f;
        float a = qreg;
        #pragma unroll
        for (int c = 0; c < 16; ++c) a += hidbuf[eq][c] * Preg[c];
        outp[(size_t)e * 8 + h] = a;
    }
}

// ---------------------------------------------------------------------------
// K2b: grid-stride reduction of ae1/ae2 per head -> sums[16]; last block
// computes self-loop mean edge scores se1/se2.
// ---------------------------------------------------------------------------
__global__ void k_redsum(const float* __restrict__ a1, const float* __restrict__ a2,
                         float* __restrict__ sums, unsigned* __restrict__ done,
                         float* __restrict__ se1, float* __restrict__ se2) {
    int tid = threadIdx.x;  // 256
    int gid = blockIdx.x * 256 + tid;
    int stride = gridDim.x * 256;
    float s1 = 0.f, s2 = 0.f;
    for (int i = gid; i < EE * 8; i += stride) { s1 += a1[i]; s2 += a2[i]; }
    for (int off = 8; off < 64; off <<= 1) { s1 += __shfl_xor(s1, off, 64); s2 += __shfl_xor(s2, off, 64); }
    __shared__ float b1[4][8], b2[4][8];
    int wid = tid >> 6, lane = tid & 63;
    if (lane < 8) { b1[wid][lane] = s1; b2[wid][lane] = s2; }
    __syncthreads();
    if (tid < 8) {
        float t1 = b1[0][tid] + b1[1][tid] + b1[2][tid] + b1[3][tid];
        float t2 = b2[0][tid] + b2[1][tid] + b2[2][tid] + b2[3][tid];
        atomicAdd(&sums[tid], t1);
        atomicAdd(&sums[8 + tid], t2);
    }
    __syncthreads();
    if (tid == 0) {
        __threadfence();
        unsigned old = atomicAdd(done, 1u);
        if (old == (unsigned)gridDim.x - 1u) {
            __threadfence();
            for (int hh = 0; hh < 8; ++hh) {
                float v1 = atomicAdd(&sums[hh], 0.f);
                float v2 = atomicAdd(&sums[8 + hh], 0.f);
                se1[hh] = v1 * (1.f / (float)EE);
                se2[hh] = v2 * (1.f / (float)EE);
            }
        }
    }
}

// ---------------------------------------------------------------------------
// CSR build by dst: scan + scatter
// ---------------------------------------------------------------------------
__global__ void k_scan(const int* __restrict__ deg, int* __restrict__ rowptr, int* __restrict__ cursor) {
    __shared__ int wsum[16];
    __shared__ int carry;
    int t = threadIdx.x, wid = t >> 6, lane = t & 63;
    if (t == 0) carry = 0;
    __syncthreads();
    for (int base = 0; base < NN; base += 1024) {
        int v = (base + t < NN) ? deg[base + t] : 0;
        int sc = v;
        #pragma unroll
        for (int off = 1; off < 64; off <<= 1) { int n = __shfl_up(sc, off, 64); if (lane >= off) sc += n; }
        if (lane == 63) wsum[wid] = sc;
        __syncthreads();
        if (t < 16) {
            int ws = wsum[t];
            #pragma unroll
            for (int off = 1; off < 16; off <<= 1) { int n = __shfl_up(ws, off, 64); if (t >= off) ws += n; }
            wsum[t] = ws;
        }
        __syncthreads();
        int ex = carry + (wid ? wsum[wid - 1] : 0) + sc - v;
        if (base + t < NN) { rowptr[base + t] = ex; cursor[base + t] = ex; }
        __syncthreads();
        if (t == 0) carry += wsum[15];
        __syncthreads();
    }
    if (t == 0) rowptr[NN] = carry;
}

__global__ void k_scatter(const int* __restrict__ ei, int* __restrict__ cursor,
                          int* __restrict__ srt_src, int* __restrict__ srt_dst) {
    int e = blockIdx.x * 256 + threadIdx.x;
    if (e < EE) {
        int d = ei[EE + e];
        int pos = atomicAdd(&cursor[d], 1);
        srt_src[pos] = ei[e];
        srt_dst[pos] = d;
    }
}

// ---------------------------------------------------------------------------
// bf16 MFMA GEMM: out_bf16[N,128] = X_bf[N,128] @ W_bf^T (+bias)
// ---------------------------------------------------------------------------
template <bool BIAS>
__global__ __launch_bounds__(256, 2) void k_mfma(const u16* __restrict__ X,
                                                 const u16* __restrict__ W,
                                                 const float* __restrict__ bias,
                                                 u16* __restrict__ out, int nrows) {
    __shared__ __align__(16) u16 tA[128 * 128];
    __shared__ __align__(16) u16 tB[128 * 128];
    int t = threadIdx.x;
    int r0 = blockIdx.x * 128;
    #pragma unroll
    for (int it = 0; it < 8; ++it) {
        int idx = it * 256 + t;
        int r = idx >> 4, u = idx & 15;
        uint4 v = make_uint4(0u, 0u, 0u, 0u);
        if (r0 + r < nrows) v = *(const uint4*)(X + (size_t)(r0 + r) * 128 + u * 8);
        *(uint4*)&tA[tswz(r, u)] = v;
        uint4 wv = *(const uint4*)(W + (size_t)r * 128 + u * 8);
        *(uint4*)&tB[tswz(r, u)] = wv;
    }
    __syncthreads();
    int l = t & 63, w = t >> 6;
    int lr = l & 15, lk = l >> 4;
    f4 acc[2][8];
    #pragma unroll
    for (int m = 0; m < 2; ++m)
        #pragma unroll
        for (int n = 0; n < 8; ++n) acc[m][n] = (f4){0.f, 0.f, 0.f, 0.f};
    #pragma unroll
    for (int s = 0; s < 4; ++s) {
        int u = s * 4 + lk;
        bf8 a0 = *(bf8*)&tA[tswz(w * 32 + lr, u)];
        bf8 a1 = *(bf8*)&tA[tswz(w * 32 + 16 + lr, u)];
        #pragma unroll
        for (int n = 0; n < 8; ++n) {
            bf8 b = *(bf8*)&tB[tswz(n * 16 + lr, u)];
            acc[0][n] = __builtin_amdgcn_mfma_f32_16x16x32_bf16(a0, b, acc[0][n], 0, 0, 0);
            acc[1][n] = __builtin_amdgcn_mfma_f32_16x16x32_bf16(a1, b, acc[1][n], 0, 0, 0);
        }
    }
    #pragma unroll
    for (int n = 0; n < 8; ++n) {
        int col = n * 16 + lr;
        float bv = BIAS ? bias[col] : 0.f;
        #pragma unroll
        for (int m = 0; m < 2; ++m) {
            #pragma unroll
            for (int g = 0; g < 4; ++g) {
                int row = r0 + w * 32 + m * 16 + lk * 4 + g;
                if (row < nrows) out[(size_t)row * 128 + col] = f2b(acc[m][n][g] + bv);
            }
        }
    }
}

// ---------------------------------------------------------------------------
// fused dual GEMM on shared A-tile: out0 = X@W0^T + b0;  out1 = X@W1^T
// ---------------------------------------------------------------------------
__global__ __launch_bounds__(256, 2) void k_mfma_x2(const u16* __restrict__ X,
                                                    const u16* __restrict__ W0,
                                                    const float* __restrict__ b0,
                                                    const u16* __restrict__ W1,
                                                    u16* __restrict__ out0,
                                                    u16* __restrict__ out1, int nrows) {
    __shared__ __align__(16) u16 tA[128 * 128];
    __shared__ __align__(16) u16 tB[128 * 128];
    int t = threadIdx.x;
    int r0 = blockIdx.x * 128;
    #pragma unroll
    for (int it = 0; it < 8; ++it) {
        int idx = it * 256 + t;
        int r = idx >> 4, u = idx & 15;
        uint4 v = make_uint4(0u, 0u, 0u, 0u);
        if (r0 + r < nrows) v = *(const uint4*)(X + (size_t)(r0 + r) * 128 + u * 8);
        *(uint4*)&tA[tswz(r, u)] = v;
        uint4 wv = *(const uint4*)(W0 + (size_t)r * 128 + u * 8);
        *(uint4*)&tB[tswz(r, u)] = wv;
    }
    __syncthreads();
    int l = t & 63, w = t >> 6;
    int lr = l & 15, lk = l >> 4;
    f4 acc[2][8];
    #pragma unroll
    for (int m = 0; m < 2; ++m)
        #pragma unroll
        for (int n = 0; n < 8; ++n) acc[m][n] = (f4){0.f, 0.f, 0.f, 0.f};
    #pragma unroll
    for (int s = 0; s < 4; ++s) {
        int u = s * 4 + lk;
        bf8 a0 = *(bf8*)&tA[tswz(w * 32 + lr, u)];
        bf8 a1 = *(bf8*)&tA[tswz(w * 32 + 16 + lr, u)];
        #pragma unroll
        for (int n = 0; n < 8; ++n) {
            bf8 b = *(bf8*)&tB[tswz(n * 16 + lr, u)];
            acc[0][n] = __builtin_amdgcn_mfma_f32_16x16x32_bf16(a0, b, acc[0][n], 0, 0, 0);
            acc[1][n] = __builtin_amdgcn_mfma_f32_16x16x32_bf16(a1, b, acc[1][n], 0, 0, 0);
        }
    }
    #pragma unroll
    for (int n = 0; n < 8; ++n) {
        int col = n * 16 + lr;
        float bv = b0[col];
        #pragma unroll
        for (int m = 0; m < 2; ++m)
            #pragma unroll
            for (int g = 0; g < 4; ++g) {
                int row = r0 + w * 32 + m * 16 + lk * 4 + g;
                if (row < nrows) out0[(size_t)row * 128 + col] = f2b(acc[m][n][g] + bv);
            }
    }
    __syncthreads();   // all reads of tB done
    #pragma unroll
    for (int it = 0; it < 8; ++it) {
        int idx = it * 256 + t;
        int r = idx >> 4, u = idx & 15;
        uint4 wv = *(const uint4*)(W1 + (size_t)r * 128 + u * 8);
        *(uint4*)&tB[tswz(r, u)] = wv;
    }
    __syncthreads();
    #pragma unroll
    for (int m = 0; m < 2; ++m)
        #pragma unroll
        for (int n = 0; n < 8; ++n) acc[m][n] = (f4){0.f, 0.f, 0.f, 0.f};
    #pragma unroll
    for (int s = 0; s < 4; ++s) {
        int u = s * 4 + lk;
        bf8 a0 = *(bf8*)&tA[tswz(w * 32 + lr, u)];
        bf8 a1 = *(bf8*)&tA[tswz(w * 32 + 16 + lr, u)];
        #pragma unroll
        for (int n = 0; n < 8; ++n) {
            bf8 b = *(bf8*)&tB[tswz(n * 16 + lr, u)];
            acc[0][n] = __builtin_amdgcn_mfma_f32_16x16x32_bf16(a0, b, acc[0][n], 0, 0, 0);
            acc[1][n] = __builtin_amdgcn_mfma_f32_16x16x32_bf16(a1, b, acc[1][n], 0, 0, 0);
        }
    }
    #pragma unroll
    for (int n = 0; n < 8; ++n) {
        int col = n * 16 + lr;
        #pragma unroll
        for (int m = 0; m < 2; ++m)
            #pragma unroll
            for (int g = 0; g < 4; ++g) {
                int row = r0 + w * 32 + m * 16 + lk * 4 + g;
                if (row < nrows) out1[(size_t)row * 128 + col] = f2b(acc[m][n][g]);
            }
    }
}

// ---------------------------------------------------------------------------
// fused JK MFMA GEMM: out_f32 = [h0 h1 h2]_bf @ jk_w_bf^T + jk_b (K=384)
// ---------------------------------------------------------------------------
__global__ __launch_bounds__(256, 2) void k_mfma_jk(const u16* __restrict__ h0,
                                                    const u16* __restrict__ h1,
                                                    const u16* __restrict__ h2,
                                                    const u16* __restrict__ W,
                                                    const float* __restrict__ bias,
                                                    float* __restrict__ out, int nrows) {
    __shared__ __align__(16) u16 tA[128 * 128];
    __shared__ __align__(16) u16 tB[128 * 128];
    int t = threadIdx.x;
    int r0 = blockIdx.x * 128;
    int l = t & 63, w = t >> 6;
    int lr = l & 15, lk = l >> 4;
    f4 acc[2][8];
    #pragma unroll
    for (int m = 0; m < 2; ++m)
        #pragma unroll
        for (int n = 0; n < 8; ++n) acc[m][n] = (f4){0.f, 0.f, 0.f, 0.f};
    for (int seg = 0; seg < 3; ++seg) {
        if (seg) __syncthreads();
        const u16* X = seg == 0 ? h0 : (seg == 1 ? h1 : h2);
        #pragma unroll
        for (int it = 0; it < 8; ++it) {
            int idx = it * 256 + t;
            int r = idx >> 4, u = idx & 15;
            uint4 v = make_uint4(0u, 0u, 0u, 0u);
            if (r0 + r < nrows) v = *(const uint4*)(X + (size_t)(r0 + r) * 128 + u * 8);
            *(uint4*)&tA[tswz(r, u)] = v;
            uint4 wv = *(const uint4*)(W + (size_t)r * 384 + seg * 128 + u * 8);
            *(uint4*)&tB[tswz(r, u)] = wv;
        }
        __syncthreads();
        #pragma unroll
        for (int s = 0; s < 4; ++s) {
            int u = s * 4 + lk;
            bf8 a0 = *(bf8*)&tA[tswz(w * 32 + lr, u)];
            bf8 a1 = *(bf8*)&tA[tswz(w * 32 + 16 + lr, u)];
            #pragma unroll
            for (int n = 0; n < 8; ++n) {
                bf8 b = *(bf8*)&tB[tswz(n * 16 + lr, u)];
                acc[0][n] = __builtin_amdgcn_mfma_f32_16x16x32_bf16(a0, b, acc[0][n], 0, 0, 0);
                acc[1][n] = __builtin_amdgcn_mfma_f32_16x16x32_bf16(a1, b, acc[1][n], 0, 0, 0);
            }
        }
    }
    #pragma unroll
    for (int n = 0; n < 8; ++n) {
        int col = n * 16 + lr;
        float bv = bias[col];
        #pragma unroll
        for (int m = 0; m < 2; ++m) {
            #pragma unroll
            for (int g = 0; g < 4; ++g) {
                int row = r0 + w * 32 + m * 16 + lk * 4 + g;
                if (row < nrows) out[(size_t)row * 128 + col] = acc[m][n][g] + bv;
            }
        }
    }
}

// ---------------------------------------------------------------------------
// per-node attention scores a_src/a_dst (wave per row, bf16 xs)
// ---------------------------------------------------------------------------
__global__ void k_att(const u16* __restrict__ xs, const float* __restrict__ att_src,
                      const float* __restrict__ att_dst,
                      float* __restrict__ a_src, float* __restrict__ a_dst) {
    int wid = threadIdx.x >> 6, lane = threadIdx.x & 63;
    int row = blockIdx.x * 4 + wid;
    if (row >= NN) return;
    const u16* xr = xs + (size_t)row * 128;
    float v0 = b2f(xr[lane]), v1 = b2f(xr[lane + 64]);
    float s0 = v0 * att_src[lane], s1 = v1 * att_src[64 + lane];
    float d0 = v0 * att_dst[lane], d1 = v1 * att_dst[64 + lane];
    for (int off = 1; off < 16; off <<= 1) {
        s0 += __shfl_xor(s0, off, 64); s1 += __shfl_xor(s1, off, 64);
        d0 += __shfl_xor(d0, off, 64); d1 += __shfl_xor(d1, off, 64);
    }
    if ((lane & 15) == 0) {
        int h = lane >> 4;
        a_src[row * 8 + h] = s0;     a_src[row * 8 + 4 + h] = s1;
        a_dst[row * 8 + h] = d0;     a_dst[row * 8 + 4 + h] = d1;
    }
}

// ---------------------------------------------------------------------------
// edge-parallel attention weights in CSR order (ae is CSR-ordered)
// ---------------------------------------------------------------------------
__global__ void k_weights(const int* __restrict__ srt_src, const int* __restrict__ srt_dst,
                          const float* __restrict__ ae, const float* __restrict__ a_src,
                          const float* __restrict__ a_dst, float* __restrict__ w) {
    int pos = blockIdx.x * 256 + threadIdx.x;
    if (pos >= EE) return;
    int s = srt_src[pos], d = srt_dst[pos];
    const float* as = a_src + (size_t)s * 8;
    const float* ad = a_dst + (size_t)d * 8;
    const float* av = ae + (size_t)pos * 8;
    float4 s0 = *(const float4*)as, s1 = *(const float4*)(as + 4);
    float4 d0 = *(const float4*)ad, d1 = *(const float4*)(ad + 4);
    float4 e0 = *(const float4*)av, e1 = *(const float4*)(av + 4);
    float al[8] = {s0.x + d0.x + e0.x, s0.y + d0.y + e0.y, s0.z + d0.z + e0.z, s0.w + d0.w + e0.w,
                   s1.x + d1.x + e1.x, s1.y + d1.y + e1.y, s1.z + d1.z + e1.z, s1.w + d1.w + e1.w};
    float o[8];
    #pragma unroll
    for (int h = 0; h < 8; ++h) {
        float a = al[h];
        a = a > 0.f ? a : 0.2f * a;
        o[h] = __expf(a);
    }
    float* wp = w + (size_t)pos * 8;
    *(float4*)wp = make_float4(o[0], o[1], o[2], o[3]);
    *(float4*)(wp + 4) = make_float4(o[4], o[5], o[6], o[7]);
}

// ---------------------------------------------------------------------------
// aggregation (precomputed weights, clamped branch-free loads) + bias + ELU +
// residual + LayerNorm. One WAVE per node, 2 features/lane, 8-deep pipeline.
// ---------------------------------------------------------------------------
#define LD(W_, X_, base_) { \
    _Pragma("unroll") \
    for (int k = 0; k < 4; ++k) { \
        int ee = (base_) + k; \
        bool ok = ee < en; \
        int cl = ok ? ee : b0; \
        int s = srt_src[cl]; \
        float wv = wq[(size_t)cl * 8 + h]; \
        W_[k] = ok ? wv : 0.f; \
        X_[k] = *(const unsigned*)(xs + (size_t)s * 128 + lane * 2); } }

#define CP(W_, X_) { \
    _Pragma("unroll") \
    for (int k = 0; k < 4; ++k) { \
        float wc = W_[k]; unsigned xv = X_[k]; \
        acc0 += wc * lo2f(xv); \
        acc1 += wc * hi2f(xv); \
        denom += wc; } }

__global__ __launch_bounds__(256) void k_agg(const int* __restrict__ rowptr,
                      const int* __restrict__ srt_src,
                      const float* __restrict__ wq,
                      const float* __restrict__ a_src, const float* __restrict__ a_dst,
                      const float* __restrict__ se,
                      const u16* __restrict__ xs, const u16* __restrict__ res,
                      const float* __restrict__ bias, const float* __restrict__ gamma,
                      const float* __restrict__ beta, u16* __restrict__ outh) {
    int wv_ = threadIdx.x >> 6, lane = threadIdx.x & 63;
    int i = blockIdx.x * 4 + wv_;
    if (i >= NN) return;
    int h = lane >> 3;                       // head of features 2*lane, 2*lane+1
    int b0 = rowptr[i], en = rowptr[i + 1];
    float acc0 = 0.f, acc1 = 0.f, denom = 0.f;
    if (b0 < en) {
        float wa[4], wb[4]; unsigned xa[4], xb_[4];
        LD(wa, xa, b0)
        LD(wb, xb_, b0 + 4)
        for (int base = b0; base < en; base += 8) {
            CP(wa, xa)
            LD(wa, xa, base + 8)
            CP(wb, xb_)
            LD(wb, xb_, base + 12)
        }
    }
    {   // self loop (mean edge-attr folded to se[h])
        float al = a_src[i * 8 + h] + a_dst[i * 8 + h] + se[h];
        al = al > 0.f ? al : 0.2f * al;
        float wc = __expf(al);
        unsigned xv = *(const unsigned*)(xs + (size_t)i * 128 + lane * 2);
        denom += wc;
        acc0 += wc * lo2f(xv);
        acc1 += wc * hi2f(xv);
    }
    float inv = 1.f / (denom + 1e-16f);
    float2 bi = *(const float2*)(bias + lane * 2);
    float v0 = acc0 * inv + bi.x;
    float v1 = acc1 * inv + bi.y;
    v0 = v0 > 0.f ? v0 : (__expf(v0) - 1.f);
    v1 = v1 > 0.f ? v1 : (__expf(v1) - 1.f);
    unsigned rv = *(const unsigned*)(res + (size_t)i * 128 + lane * 2);
    v0 += lo2f(rv);
    v1 += hi2f(rv);
    float s = v0 + v1, q = v0 * v0 + v1 * v1;
    #pragma unroll
    for (int off = 1; off < 64; off <<= 1) { s += __shfl_xor(s, off, 64); q += __shfl_xor(q, off, 64); }
    float mu = s * (1.f / 128.f);
    float var = q * (1.f / 128.f) - mu * mu;
    float r = rsqrtf(var + 1e-5f);
    float2 ga = *(const float2*)(gamma + lane * 2);
    float2 be = *(const float2*)(beta + lane * 2);
    float o0 = (v0 - mu) * r * ga.x + be.x;
    float o1 = (v1 - mu) * r * ga.y + be.y;
    unsigned ov = (unsigned)f2b(o0) | ((unsigned)f2b(o1) << 16);
    *(unsigned*)(outh + (size_t)i * 128 + lane * 2) = ov;
}

// ---------------------------------------------------------------------------
extern "C" void kernel_launch(void* const* d_in, const int* in_sizes, int n_in,
                              void* d_out, int out_size, void* d_ws, size_t ws_size,
                              hipStream_t stream) {
    const float* x        = (const float*)d_in[0];
    const int*   ei       = (const int*)d_in[1];
    const float* enc_w1   = (const float*)d_in[2];
    const float* enc_b1   = (const float*)d_in[3];
    const float* enc_w2   = (const float*)d_in[4];
    const float* enc_b2   = (const float*)d_in[5];
    const float* in_w     = (const float*)d_in[6];
    const float* in_b     = (const float*)d_in[7];
    const float* lin_w1   = (const float*)d_in[8];
    const float* att_src1 = (const float*)d_in[9];
    const float* att_dst1 = (const float*)d_in[10];
    const float* att_edge1= (const float*)d_in[11];
    const float* lin_ew1  = (const float*)d_in[12];
    const float* bias1    = (const float*)d_in[13];
    const float* lin_w2   = (const float*)d_in[14];
    const float* att_src2 = (const float*)d_in[15];
    const float* att_dst2 = (const float*)d_in[16];
    const float* att_edge2= (const float*)d_in[17];
    const float* lin_ew2  = (const float*)d_in[18];
    const float* bias2    = (const float*)d_in[19];
    const float* g1       = (const float*)d_in[20];
    const float* bn1      = (const float*)d_in[21];
    const float* g2       = (const float*)d_in[22];
    const float* bn2      = (const float*)d_in[23];
    const float* jk_w     = (const float*)d_in[24];
    const float* jk_b     = (const float*)d_in[25];
    float* out = (float*)d_out;

    char* wsp = (char*)d_ws;
    size_t off = 0;
    auto alloc = [&](size_t bytes) -> char* {
        char* p = wsp + off;
        off += (bytes + 255) & ~(size_t)255;
        return p;
    };
    u16* x_bf   = (u16*)alloc(sizeof(u16) * (size_t)NN * 128);
    u16* h0b    = (u16*)alloc(sizeof(u16) * (size_t)NN * 128);
    u16* h1b    = (u16*)alloc(sizeof(u16) * (size_t)NN * 128);
    u16* h2b    = (u16*)alloc(sizeof(u16) * (size_t)NN * 128);
    u16* xsb    = (u16*)alloc(sizeof(u16) * (size_t)NN * 128);
    u16* inw_b  = (u16*)alloc(sizeof(u16) * 16384);
    u16* w1_b   = (u16*)alloc(sizeof(u16) * 16384);
    u16* w2_b   = (u16*)alloc(sizeof(u16) * 16384);
    u16* jkw_b  = (u16*)alloc(sizeof(u16) * 49152);
    float* ae1   = (float*)alloc(sizeof(float) * (size_t)EE * 8);
    float* ae2   = (float*)alloc(sizeof(float) * (size_t)EE * 8);
    float* wbuf  = (float*)alloc(sizeof(float) * (size_t)EE * 8);
    float* norms = (float*)alloc(sizeof(float) * NN);
    float* a_src1= (float*)alloc(sizeof(float) * NN * 8);
    float* a_dst1= (float*)alloc(sizeof(float) * NN * 8);
    float* a_src2= (float*)alloc(sizeof(float) * NN * 8);
    float* a_dst2= (float*)alloc(sizeof(float) * NN * 8);
    float* P1    = (float*)alloc(sizeof(float) * 128);
    float* q1    = (float*)alloc(sizeof(float) * 8);
    float* P2    = (float*)alloc(sizeof(float) * 128);
    float* q2    = (float*)alloc(sizeof(float) * 8);
    float* se1   = (float*)alloc(sizeof(float) * 8);
    float* se2   = (float*)alloc(sizeof(float) * 8);
    // zero-init region: deg + sums + done contiguous, single memset
    int* deg     = (int*)alloc(sizeof(int) * NN);
    float* sums  = (float*)alloc(sizeof(float) * 16);
    unsigned* done = (unsigned*)alloc(sizeof(unsigned));
    int* rowptr  = (int*)alloc(sizeof(int) * (NN + 1));
    int* cursor  = (int*)alloc(sizeof(int) * NN);
    int* srt_src = (int*)alloc(sizeof(int) * EE);
    int* srt_dst = (int*)alloc(sizeof(int) * EE);
    (void)ws_size; (void)in_sizes; (void)n_in; (void)out_size;

    hipMemsetAsync(deg, 0, (size_t)((char*)rowptr - (char*)deg), stream);

    // mega prep: node norms/cvt + weight cvt + precompute + degree hist
    k_prep<<<NBP + 48 + 1 + (EE + 255) / 256, 256, 0, stream>>>(
        x, norms, x_bf,
        in_w, inw_b, lin_w1, w1_b, lin_w2, w2_b, jk_w, jkw_b,
        lin_ew1, att_edge1, lin_ew2, att_edge2, enc_w2, enc_b2, P1, q1, P2, q2,
        ei, deg);
    k_scan<<<1, 1024, 0, stream>>>(deg, rowptr, cursor);
    k_scatter<<<(EE + 255) / 256, 256, 0, stream>>>(ei, cursor, srt_src, srt_dst);
    k_encoder<<<EE / 64, 256, 0, stream>>>(x_bf, srt_src, srt_dst, norms, enc_w1, enc_b1,
                                           P1, q1, P2, q2, ae1, ae2);
    k_redsum<<<128, 256, 0, stream>>>(ae1, ae2, sums, done, se1, se2);

    int gm = (NN + 127) / 128;
    k_mfma_x2<<<gm, 256, 0, stream>>>(x_bf, inw_b, in_b, w1_b, h0b, xsb, NN);
    k_att<<<(NN + 3) / 4, 256, 0, stream>>>(xsb, att_src1, att_dst1, a_src1, a_dst1);
    k_weights<<<(EE + 255) / 256, 256, 0, stream>>>(srt_src, srt_dst, ae1,
                                                    a_src1, a_dst1, wbuf);
    k_agg<<<(NN + 3) / 4, 256, 0, stream>>>(rowptr, srt_src, wbuf, a_src1, a_dst1, se1,
                                            xsb, h0b, bias1, g1, bn1, h1b);
    k_mfma<false><<<gm, 256, 0, stream>>>(h1b, w2_b, nullptr, xsb, NN);
    k_att<<<(NN + 3) / 4, 256, 0, stream>>>(xsb, att_src2, att_dst2, a_src2, a_dst2);
    k_weights<<<(EE + 255) / 256, 256, 0, stream>>>(srt_src, srt_dst, ae2,
                                                    a_src2, a_dst2, wbuf);
    k_agg<<<(NN + 3) / 4, 256, 0, stream>>>(rowptr, srt_src, wbuf, a_src2, a_dst2, se2,
                                            xsb, h1b, bias2, g2, bn2, h2b);
    k_mfma_jk<<<gm, 256, 0, stream>>>(h0b, h1b, h2b, jkw_b, jk_b, out, NN);
}